// Round 9
// baseline (6585.146 us; speedup 1.0000x reference)
//
#include <hip/hip_runtime.h>
#include <math.h>

// Problem constants
#define NB   2048   // batch
#define SEQ  64
#define CIN  142
#define DM   256
#define NH   8
#define DHD  32
#define FFD  512
#define NL   3
#define ED   128
#define KCB  1024
#define TT   65     // SEQ+1 (cls prepended)
#define NT   1024   // threads per block (R9: 16 waves -> 4 waves/SIMD)
#define NW   16     // waves per block

// Preconverted-weights workspace layout (floats 0..1055 = header):
//   ws[0] commitment, ws[1..1024] histogram, pad to 1056.
//   PH = (_Float16*)(ws+1056): hi plane [E_TOT]; PL = PH + E_TOT: lo plane.
#define E_TOT    1572864
#define OFF_WO   589824
#define OFF_W1   786432
#define OFF_W2   1179648
#define WS_NEED  (4224 + 4 * E_TOT)  // bytes

typedef __attribute__((ext_vector_type(4))) float f32x4;
typedef __attribute__((ext_vector_type(8))) _Float16 f16x8;
typedef __attribute__((ext_vector_type(4))) _Float16 f16x4;
typedef __attribute__((ext_vector_type(2))) _Float16 f16x2;

// ---- split-fp16: x = hi + lo*2^-11, both fp16; lo pre-scaled by 2^11.
//   C = Whi*Ahi + (Whi*Alo' + Wlo'*Ahi) * 2^-11   (lo*lo ~2^-22, dropped)
// Activations live as hi/lo f16 pair arrays in LDS; weights preconverted to
// f16 pair planes in d_ws (fallback: in-loop split).
// R9: 1024 threads = 16 waves = 4 waves/SIMD. The allocator pins 128 VGPRs
// (budget for 4 waves/EU); at 8 waves we only ran 2/EU and paid the reg tax
// without the occupancy. LDS/block unchanged (1 block/CU). All gemm calls
// keep R7-proven spill-free shapes (TTN<=2, CIT<=2) spread over 16 waves.
// R6/R7/R8 sweep: TTN=5 spill 5.29ms / TTN=3 spill 5.82 / TTN=2 clean 7.03
// -> 8-wave envelope exhausted; this doubles TLP instead.
#define LO_SCALE 2048.0f
#define LO_INV   (1.0f / 2048.0f)

__device__ __forceinline__ float gelu_f(float x) {
  return 0.5f * x * (1.0f + erff(x * 0.70710678118654752f));
}

__device__ __forceinline__ float wave_bsum(float v) {
#pragma unroll
  for (int off = 32; off >= 1; off >>= 1) v += __shfl_xor(v, off, 64);
  return v;
}
__device__ __forceinline__ float wave_bmax(float v) {
#pragma unroll
  for (int off = 32; off >= 1; off >>= 1) v = fmaxf(v, __shfl_xor(v, off, 64));
  return v;
}

// Swizzled pair-array index (pitch in halves, multiple of 64): 16B slots
// (8 halves) XORed by (row&7) -> rows spread over all 8 bank groups.
__device__ __forceinline__ int pidx(int pitch, int t, int c) {
  return t * pitch + ((((c >> 3) ^ (t & 7)) << 3) | (c & 7));
}

__device__ __forceinline__ void split4v(f32x4 v, f16x4& hi, f16x4& lo) {
#pragma unroll
  for (int j = 0; j < 4; ++j) {
    _Float16 h = (_Float16)v[j];
    hi[j] = h;
    lo[j] = (_Float16)((v[j] - (float)h) * LO_SCALE);
  }
}

__device__ __forceinline__ void pair_store4(_Float16* dH, _Float16* dL, int pitch,
                                            int t, int o, f32x4 v) {
  f16x4 hi, lo;
  split4v(v, hi, lo);
  int off = pidx(pitch, t, o);
  *(f16x4*)&dH[off] = hi;
  *(f16x4*)&dL[off] = lo;
}
__device__ __forceinline__ f32x4 pair_load4(const _Float16* dH, const _Float16* dL,
                                            int pitch, int t, int o) {
  int off = pidx(pitch, t, o);
  f16x4 hi = *(const f16x4*)&dH[off];
  f16x4 lo = *(const f16x4*)&dL[off];
  f32x4 v;
#pragma unroll
  for (int j = 0; j < 4; ++j) v[j] = (float)hi[j] + (float)lo[j] * LO_INV;
  return v;
}

// 8 f32 (array) -> split f16x8 pair
__device__ __forceinline__ void split8_arr(const float* vv, f16x8& hi, f16x8& lo) {
#pragma unroll
  for (int j = 0; j < 8; ++j) {
    _Float16 h = (_Float16)vv[j];
    hi[j] = h;
    lo[j] = (_Float16)((vv[j] - (float)h) * LO_SCALE);
  }
}
// 8 consecutive f32 (16B-aligned) -> split pair
__device__ __forceinline__ void split8_f4(const float* p, f16x8& hi, f16x8& lo) {
  float4 v0 = *(const float4*)p;
  float4 v1 = *(const float4*)(p + 4);
  float vv[8] = {v0.x, v0.y, v0.z, v0.w, v1.x, v1.y, v1.z, v1.w};
  split8_arr(vv, hi, lo);
}
// 8 consecutive f32 (8B-aligned) -> split pair
__device__ __forceinline__ void split8_f2(const float* p, f16x8& hi, f16x8& lo) {
  float vv[8];
#pragma unroll
  for (int j = 0; j < 4; ++j) {
    float2 v = *(const float2*)(p + 2 * j);
    vv[2 * j] = v.x;
    vv[2 * j + 1] = v.y;
  }
  split8_arr(vv, hi, lo);
}

// ---------- barrier-free MFMA GEMM: per-wave o-tiles, ot0 resolved by caller.
// C[T][O] += A[T][K] * W[O][K]^T. A: split-pair in LDS (swizzled, pitch
// apitch; base row multiple of 8). W: WMODE 0 = f32 guarded scalar (embed);
// 1 = f32 aligned reg-split; 2 = preconverted f16 pair planes.
// Wave's tiles: {ot0 + otstride*ci}; ot0 < 0 -> idle (wave-uniform).
// Operand-swapped MFMA: D[o_loc = (lane>>4)*4+reg][t = lane&15].
// R9 contract: TTN<=2, CIT<=2 (R7-proven spill-free at 128 VGPRs).
template <int TTN, int CIT, int WMODE>
__device__ __forceinline__ void mfma_gw(
    f32x4 (&acc1)[CIT][TTN], f32x4 (&acc2)[CIT][TTN],
    const float* __restrict__ Wg, const _Float16* __restrict__ WgH,
    const _Float16* __restrict__ WgL, int wld, int rbase, int rsel,
    int ot0, int otstride,
    const _Float16* aH, const _Float16* aL, int apitch, int tRows,
    int kdim, int kvalid, int lane) {
  if (ot0 < 0) return;
  const int q4 = lane >> 4, cl = lane & 15;
  int wrow[CIT];
#pragma unroll
  for (int ci = 0; ci < CIT; ++ci) {
    int r = (ot0 + otstride * ci) * 16 + cl;
    wrow[ci] = (rbase + (r & 31) + rsel * (r >> 5)) * wld;
  }
  f16x8 zf;
#pragma unroll
  for (int j = 0; j < 8; ++j) zf[j] = (_Float16)0.f;
#pragma unroll 1
  for (int kc = 0; kc < kdim; kc += 32) {
    f16x8 bh[CIT], bl[CIT];
#pragma unroll
    for (int ci = 0; ci < CIT; ++ci) {
      if (WMODE == 2) {
        int off = wrow[ci] + kc + 8 * q4;
        bh[ci] = *(const f16x8*)&WgH[off];
        bl[ci] = *(const f16x8*)&WgL[off];
      } else if (WMODE == 1) {
        split8_f4(Wg + wrow[ci] + kc + 8 * q4, bh[ci], bl[ci]);
      } else {  // embed: wld=142 unaligned + k tail guard
        const float* wp = Wg + wrow[ci] + kc + 8 * q4;
        int cb = kc + 8 * q4;
        float vv[8];
#pragma unroll
        for (int j = 0; j < 8; ++j) vv[j] = (cb + j < kvalid) ? wp[j] : 0.f;
        split8_arr(vv, bh[ci], bl[ci]);
      }
    }
#pragma unroll
    for (int tt = 0; tt < TTN; ++tt) {
      int t = 16 * tt + cl;
      f16x8 ah, al;
      if (t < tRows) {
        int off = t * apitch + (((((kc >> 3) + q4) ^ (t & 7))) << 3);
        ah = *(const f16x8*)&aH[off];
        al = *(const f16x8*)&aL[off];
      } else {
        ah = zf;
        al = zf;
      }
#pragma unroll
      for (int ci = 0; ci < CIT; ++ci) {
        acc1[ci][tt] = __builtin_amdgcn_mfma_f32_16x16x32_f16(bh[ci], ah, acc1[ci][tt], 0, 0, 0);
        acc2[ci][tt] = __builtin_amdgcn_mfma_f32_16x16x32_f16(bh[ci], al, acc2[ci][tt], 0, 0, 0);
        acc2[ci][tt] = __builtin_amdgcn_mfma_f32_16x16x32_f16(bl[ci], ah, acc2[ci][tt], 0, 0, 0);
      }
    }
  }
}

// qkv epilogue: write Q/K/VT (+t=64 extras) for o-tile ot, rows [base, base+tvalid)
__device__ __forceinline__ void qkv_epi2(const f32x4* a1, const f32x4* a2,
                                         int nt, int base, int tvalid, int ot,
                                         const float* __restrict__ bqkv_l, int hd,
                                         float* Qf, float* Kf, float* VT,
                                         float* ex, int lane) {
  const int q4 = lane >> 4, cl = lane & 15;
  for (int tt = 0; tt < nt; ++tt) {
    int tl = 16 * tt + cl;
    if (tl < tvalid) {
      int t = base + tl;
#pragma unroll
      for (int rg = 0; rg < 4; ++rg) {
        int c = ot * 16 + q4 * 4 + rg;  // 0..95
        int d = c & 31;
        float v = a1[tt][rg] + a2[tt][rg] * LO_INV +
                  bqkv_l[(c >> 5) * 256 + hd * 32 + d];
        if (c < 32)      { if (t < 64) Qf[t * 36 + d] = v; else ex[d] = v; }
        else if (c < 64) { if (t < 64) Kf[t * 36 + d] = v; else ex[32 + d] = v; }
        else             VT[d * 66 + t] = v;
      }
    }
  }
}

// proj epilogue: h += acc + bias; o-tile ot (16 cols), rows [base, base+tvalid)
__device__ __forceinline__ void proj_epi2(const f32x4* a1, const f32x4* a2,
                                          int nt, int base, int tvalid, int ot,
                                          const float* __restrict__ bo_l,
                                          _Float16* hH, _Float16* hL, int lane) {
  const int q4 = lane >> 4, cl = lane & 15;
  for (int tt = 0; tt < nt; ++tt) {
    int tl = 16 * tt + cl;
    if (tl < tvalid) {
      int t = base + tl;
      int o = ot * 16 + q4 * 4;
      f32x4 r = pair_load4(hH, hL, 256, t, o);
      float4 b4 = *(const float4*)&bo_l[o];
      float bb[4] = {b4.x, b4.y, b4.z, b4.w};
      f32x4 v;
#pragma unroll
      for (int rg = 0; rg < 4; ++rg)
        v[rg] = r[rg] + a1[tt][rg] + a2[tt][rg] * LO_INV + bb[rg];
      pair_store4(hH, hL, 256, t, o, v);
    }
  }
}

// qkv phase: 18 tasks over 16 waves (12 big TTN=2 + 6 small TTN=1; waves
// 12,13 take a second small). Gemms touch only h + W; barrier (1) separates
// prev head's Sb/VT reads from the scr epilogue writes.
template <int WM>
__device__ __forceinline__ void qkv_phase(
    const float* __restrict__ Wq, const _Float16* __restrict__ WqH,
    const _Float16* __restrict__ WqL, const float* __restrict__ bqkv_l, int hd,
    const _Float16* hH, const _Float16* hL,
    float* Qf, float* Kf, float* VT, float* ex, int wave, int lane) {
  const f32x4 Z4 = {0.f, 0.f, 0.f, 0.f};
  f32x4 b1a[1][2], b2a[1][2], s1a[1][1], s2a[1][1], s1b[1][1], s2b[1][1];
#pragma unroll
  for (int tt = 0; tt < 2; ++tt) { b1a[0][tt] = Z4; b2a[0][tt] = Z4; }
  s1a[0][0] = Z4; s2a[0][0] = Z4; s1b[0][0] = Z4; s2b[0][0] = Z4;
  const int bigot = (wave < 12) ? (wave >> 1) : -1;
  const int bigbase = (wave & 1) * 32;
  const int sot1 = (wave >= 12) ? (wave - 12) : -1;
  const int sot2 = (wave == 12) ? 4 : ((wave == 13) ? 5 : -1);
  mfma_gw<2, 1, WM>(b1a, b2a, Wq, WqH, WqL, DM, hd * 32, 256, bigot, 16,
                    hH + bigbase * 256, hL + bigbase * 256, 256, 32, DM, DM,
                    lane);
  mfma_gw<1, 1, WM>(s1a, s2a, Wq, WqH, WqL, DM, hd * 32, 256, sot1, 16,
                    hH + 64 * 256, hL + 64 * 256, 256, 1, DM, DM, lane);
  mfma_gw<1, 1, WM>(s1b, s2b, Wq, WqH, WqL, DM, hd * 32, 256, sot2, 16,
                    hH + 64 * 256, hL + 64 * 256, 256, 1, DM, DM, lane);
  __syncthreads();  // (1) prev head's Sb/VT reads done; scr writable
  if (bigot >= 0)
    qkv_epi2(&b1a[0][0], &b2a[0][0], 2, bigbase, 32, bigot, bqkv_l, hd,
             Qf, Kf, VT, ex, lane);
  if (sot1 >= 0)
    qkv_epi2(&s1a[0][0], &s2a[0][0], 1, 64, 1, sot1, bqkv_l, hd,
             Qf, Kf, VT, ex, lane);
  if (sot2 >= 0)
    qkv_epi2(&s1b[0][0], &s2b[0][0], 1, 64, 1, sot2, bqkv_l, hd,
             Qf, Kf, VT, ex, lane);
}

// proj: wave = o-tile (16 tiles x 16 cols); rows {32,32,1}; K=256 each.
template <int WM>
__device__ __forceinline__ void proj_phase(
    const float* __restrict__ Wo_l, const _Float16* __restrict__ WoH,
    const _Float16* __restrict__ WoL, const float* __restrict__ bo_l,
    const _Float16* oH, const _Float16* oL,
    _Float16* hH, _Float16* hL, int wave, int lane) {
  const f32x4 Z4 = {0.f, 0.f, 0.f, 0.f};
  {
    f32x4 a1[1][2], a2[1][2];
#pragma unroll
    for (int tt = 0; tt < 2; ++tt) { a1[0][tt] = Z4; a2[0][tt] = Z4; }
    mfma_gw<2, 1, WM>(a1, a2, Wo_l, WoH, WoL, DM, 0, 32, wave, 16,
                      oH, oL, 256, 32, DM, DM, lane);
    proj_epi2(&a1[0][0], &a2[0][0], 2, 0, 32, wave, bo_l, hH, hL, lane);
  }
  {
    f32x4 a1[1][2], a2[1][2];
#pragma unroll
    for (int tt = 0; tt < 2; ++tt) { a1[0][tt] = Z4; a2[0][tt] = Z4; }
    mfma_gw<2, 1, WM>(a1, a2, Wo_l, WoH, WoL, DM, 0, 32, wave, 16,
                      oH + 32 * 256, oL + 32 * 256, 256, 32, DM, DM, lane);
    proj_epi2(&a1[0][0], &a2[0][0], 2, 32, 32, wave, bo_l, hH, hL, lane);
  }
  {
    f32x4 a1[1][1], a2[1][1];
    a1[0][0] = Z4; a2[0][0] = Z4;
    mfma_gw<1, 1, WM>(a1, a2, Wo_l, WoH, WoL, DM, 0, 32, wave, 16,
                      oH + 64 * 256, oL + 64 * 256, 256, 1, DM, DM, lane);
    proj_epi2(&a1[0][0], &a2[0][0], 1, 64, 1, wave, bo_l, hH, hL, lane);
  }
}

// FF pass 0: rows [0,32). FF1: 32 o-tiles {w, w+16} CIT=2; FF2: 16 o-tiles.
template <int WM>
__device__ __forceinline__ void ff_pass0(
    const float* __restrict__ W1_l, const float* __restrict__ b1_l,
    const float* __restrict__ W2_l, const float* __restrict__ b2_l,
    const _Float16* __restrict__ W1H, const _Float16* __restrict__ W1L,
    const _Float16* __restrict__ W2H, const _Float16* __restrict__ W2L,
    _Float16* hH, _Float16* hL, _Float16* f1H, _Float16* f1L,
    int wave, int lane) {
  const int q4 = lane >> 4, cl = lane & 15;
  const f32x4 Z4 = {0.f, 0.f, 0.f, 0.f};
  {
    f32x4 a1[2][2], a2[2][2];
#pragma unroll
    for (int ci = 0; ci < 2; ++ci)
#pragma unroll
      for (int tt = 0; tt < 2; ++tt) { a1[ci][tt] = Z4; a2[ci][tt] = Z4; }
    mfma_gw<2, 2, WM>(a1, a2, W1_l, W1H, W1L, DM, 0, 32, wave, 16,
                      hH, hL, 256, 32, DM, DM, lane);
#pragma unroll
    for (int ci = 0; ci < 2; ++ci)
#pragma unroll
      for (int tt = 0; tt < 2; ++tt) {
        int t = 16 * tt + cl;
        int m = (wave + 16 * ci) * 16 + q4 * 4;
        float4 b4 = *(const float4*)&b1_l[m];
        float bb[4] = {b4.x, b4.y, b4.z, b4.w};
        f32x4 v;
#pragma unroll
        for (int rg = 0; rg < 4; ++rg)
          v[rg] = gelu_f(a1[ci][tt][rg] + a2[ci][tt][rg] * LO_INV + bb[rg]);
        pair_store4(f1H, f1L, 512, t, m, v);
      }
  }
  __syncthreads();  // f1 ready
  {
    f32x4 a1[1][2], a2[1][2];
#pragma unroll
    for (int tt = 0; tt < 2; ++tt) { a1[0][tt] = Z4; a2[0][tt] = Z4; }
    mfma_gw<2, 1, WM>(a1, a2, W2_l, W2H, W2L, FFD, 0, 32, wave, 16,
                      f1H, f1L, 512, 32, FFD, FFD, lane);
#pragma unroll
    for (int tt = 0; tt < 2; ++tt) {
      int t = 16 * tt + cl;
      int o = wave * 16 + q4 * 4;
      f32x4 r = pair_load4(hH, hL, 256, t, o);
      float4 b4 = *(const float4*)&b2_l[o];
      float bb[4] = {b4.x, b4.y, b4.z, b4.w};
      f32x4 v;
#pragma unroll
      for (int rg = 0; rg < 4; ++rg)
        v[rg] = r[rg] + a1[0][tt][rg] + a2[0][tt][rg] * LO_INV + bb[rg];
      pair_store4(hH, hL, 256, t, o, v);
    }
  }
}

// FF pass 1: rows [32,65) (f1 local rows 0..32). Row-calls {TTN=2/32, TTN=1/1}.
template <int WM>
__device__ __forceinline__ void ff_pass1(
    const float* __restrict__ W1_l, const float* __restrict__ b1_l,
    const float* __restrict__ W2_l, const float* __restrict__ b2_l,
    const _Float16* __restrict__ W1H, const _Float16* __restrict__ W1L,
    const _Float16* __restrict__ W2H, const _Float16* __restrict__ W2L,
    _Float16* hH, _Float16* hL, _Float16* f1H, _Float16* f1L,
    int wave, int lane) {
  const int q4 = lane >> 4, cl = lane & 15;
  const f32x4 Z4 = {0.f, 0.f, 0.f, 0.f};
  {
    f32x4 a1[2][2], a2[2][2];
#pragma unroll
    for (int ci = 0; ci < 2; ++ci)
#pragma unroll
      for (int tt = 0; tt < 2; ++tt) { a1[ci][tt] = Z4; a2[ci][tt] = Z4; }
    mfma_gw<2, 2, WM>(a1, a2, W1_l, W1H, W1L, DM, 0, 32, wave, 16,
                      hH + 32 * 256, hL + 32 * 256, 256, 32, DM, DM, lane);
#pragma unroll
    for (int ci = 0; ci < 2; ++ci)
#pragma unroll
      for (int tt = 0; tt < 2; ++tt) {
        int tl = 16 * tt + cl;  // f1 local row 0..31
        int m = (wave + 16 * ci) * 16 + q4 * 4;
        float4 b4 = *(const float4*)&b1_l[m];
        float bb[4] = {b4.x, b4.y, b4.z, b4.w};
        f32x4 v;
#pragma unroll
        for (int rg = 0; rg < 4; ++rg)
          v[rg] = gelu_f(a1[ci][tt][rg] + a2[ci][tt][rg] * LO_INV + bb[rg]);
        pair_store4(f1H, f1L, 512, tl, m, v);
      }
    f32x4 c1[2][1], c2[2][1];
#pragma unroll
    for (int ci = 0; ci < 2; ++ci) { c1[ci][0] = Z4; c2[ci][0] = Z4; }
    mfma_gw<1, 2, WM>(c1, c2, W1_l, W1H, W1L, DM, 0, 32, wave, 16,
                      hH + 64 * 256, hL + 64 * 256, 256, 1, DM, DM, lane);
#pragma unroll
    for (int ci = 0; ci < 2; ++ci) {
      if (cl < 1) {  // f1 local row 32
        int m = (wave + 16 * ci) * 16 + q4 * 4;
        float4 b4 = *(const float4*)&b1_l[m];
        float bb[4] = {b4.x, b4.y, b4.z, b4.w};
        f32x4 v;
#pragma unroll
        for (int rg = 0; rg < 4; ++rg)
          v[rg] = gelu_f(c1[ci][0][rg] + c2[ci][0][rg] * LO_INV + bb[rg]);
        pair_store4(f1H, f1L, 512, 32, m, v);
      }
    }
  }
  __syncthreads();  // f1 ready
  {
    f32x4 a1[1][2], a2[1][2];
#pragma unroll
    for (int tt = 0; tt < 2; ++tt) { a1[0][tt] = Z4; a2[0][tt] = Z4; }
    mfma_gw<2, 1, WM>(a1, a2, W2_l, W2H, W2L, FFD, 0, 32, wave, 16,
                      f1H, f1L, 512, 32, FFD, FFD, lane);
#pragma unroll
    for (int tt = 0; tt < 2; ++tt) {
      int t = 32 + 16 * tt + cl;
      int o = wave * 16 + q4 * 4;
      f32x4 r = pair_load4(hH, hL, 256, t, o);
      float4 b4 = *(const float4*)&b2_l[o];
      float bb[4] = {b4.x, b4.y, b4.z, b4.w};
      f32x4 v;
#pragma unroll
      for (int rg = 0; rg < 4; ++rg)
        v[rg] = r[rg] + a1[0][tt][rg] + a2[0][tt][rg] * LO_INV + bb[rg];
      pair_store4(hH, hL, 256, t, o, v);
    }
    f32x4 c1[1][1], c2[1][1];
    c1[0][0] = Z4; c2[0][0] = Z4;
    mfma_gw<1, 1, WM>(c1, c2, W2_l, W2H, W2L, FFD, 0, 32, wave, 16,
                      f1H + 32 * 512, f1L + 32 * 512, 512, 1, FFD, FFD, lane);
    if (cl < 1) {
      int o = wave * 16 + q4 * 4;
      f32x4 r = pair_load4(hH, hL, 256, 64, o);
      float4 b4 = *(const float4*)&b2_l[o];
      float bb[4] = {b4.x, b4.y, b4.z, b4.w};
      f32x4 v;
#pragma unroll
      for (int rg = 0; rg < 4; ++rg)
        v[rg] = r[rg] + c1[0][0][rg] + c2[0][0][rg] * LO_INV + bb[rg];
      pair_store4(hH, hL, 256, 64, o, v);
    }
  }
}

// LayerNorm on the pair-stored residual stream
__device__ __forceinline__ void ln_rows_pair(_Float16* hH, _Float16* hL,
                                             const float* g, const float* be,
                                             int wave, int lane) {
  for (int t = wave; t < TT; t += NW) {
    int c0 = 2 * lane, c1 = 128 + 2 * lane;
    int o0 = pidx(256, t, c0), o1 = pidx(256, t, c1);
    f16x2 h0 = *(f16x2*)&hH[o0], l0 = *(f16x2*)&hL[o0];
    f16x2 h1 = *(f16x2*)&hH[o1], l1 = *(f16x2*)&hL[o1];
    float v0 = (float)h0[0] + (float)l0[0] * LO_INV;
    float v1 = (float)h0[1] + (float)l0[1] * LO_INV;
    float v2 = (float)h1[0] + (float)l1[0] * LO_INV;
    float v3 = (float)h1[1] + (float)l1[1] * LO_INV;
    float m = wave_bsum(v0 + v1 + v2 + v3) * (1.0f / 256.0f);
    float d0 = v0 - m, d1 = v1 - m, d2 = v2 - m, d3 = v3 - m;
    float var = wave_bsum(d0 * d0 + d1 * d1 + d2 * d2 + d3 * d3) * (1.0f / 256.0f);
    float rstd = 1.0f / sqrtf(var + 1e-5f);
    float2 g0 = *(const float2*)&g[c0], g1 = *(const float2*)&g[c1];
    float2 b0 = *(const float2*)&be[c0], b1 = *(const float2*)&be[c1];
    float r0 = d0 * rstd * g0.x + b0.x;
    float r1 = d1 * rstd * g0.y + b0.y;
    float r2 = d2 * rstd * g1.x + b1.x;
    float r3 = d3 * rstd * g1.y + b1.y;
    f16x2 nh0, nl0, nh1, nl1;
    nh0[0] = (_Float16)r0; nl0[0] = (_Float16)((r0 - (float)nh0[0]) * LO_SCALE);
    nh0[1] = (_Float16)r1; nl0[1] = (_Float16)((r1 - (float)nh0[1]) * LO_SCALE);
    nh1[0] = (_Float16)r2; nl1[0] = (_Float16)((r2 - (float)nh1[0]) * LO_SCALE);
    nh1[1] = (_Float16)r3; nl1[1] = (_Float16)((r3 - (float)nh1[1]) * LO_SCALE);
    *(f16x2*)&hH[o0] = nh0; *(f16x2*)&hL[o0] = nl0;
    *(f16x2*)&hH[o1] = nh1; *(f16x2*)&hL[o1] = nl1;
  }
}

__global__ void vqvae_zero(float* __restrict__ ws) {
  int i = blockIdx.x * blockDim.x + threadIdx.x;
  if (i < 1025) ws[i] = 0.f;
}

// Preconvert layer weights into split-f16 planes in ws (once per dispatch).
__global__ void vqvae_prep(const float* __restrict__ Wqkv,
                           const float* __restrict__ Wo,
                           const float* __restrict__ W1,
                           const float* __restrict__ W2,
                           float* __restrict__ ws) {
  _Float16* PH = (_Float16*)(ws + 1056);
  _Float16* PL = PH + E_TOT;
  for (int i = blockIdx.x * blockDim.x + threadIdx.x; i < E_TOT;
       i += gridDim.x * blockDim.x) {
    float v;
    if (i < OFF_WO)      v = Wqkv[i];
    else if (i < OFF_W1) v = Wo[i - OFF_WO];
    else if (i < OFF_W2) v = W1[i - OFF_W1];
    else                 v = W2[i - OFF_W2];
    _Float16 h = (_Float16)v;
    PH[i] = h;
    PL[i] = (_Float16)((v - (float)h) * LO_SCALE);
  }
}

// LDS (161,216 B) -> 1 block/CU; 16 waves/block = 4 waves/SIMD (matches the
// allocator's 128-VGPR / 4-waves-per-EU budget).
__global__ __attribute__((amdgpu_flat_work_group_size(1024, 1024), amdgpu_waves_per_eu(4, 4)))
void vqvae_main(
    const float* __restrict__ x, const float* __restrict__ W_in,
    const float* __restrict__ b_in, const float* __restrict__ cls_token,
    const float* __restrict__ Wqkv, const float* __restrict__ bqkv,
    const float* __restrict__ Wo, const float* __restrict__ bo,
    const float* __restrict__ W1, const float* __restrict__ b1,
    const float* __restrict__ W2, const float* __restrict__ b2,
    const float* __restrict__ ln1_g, const float* __restrict__ ln1_b,
    const float* __restrict__ ln2_g, const float* __restrict__ ln2_b,
    const float* __restrict__ lnf_g, const float* __restrict__ lnf_b,
    const float* __restrict__ W_out, const float* __restrict__ b_out,
    const float* __restrict__ codebook, const float* __restrict__ Wd1,
    const float* __restrict__ bd1, const float* __restrict__ lnd_g,
    const float* __restrict__ lnd_b, const float* __restrict__ Wd2,
    const float* __restrict__ bd2, const float* __restrict__ Wd3,
    const float* __restrict__ bd3, float* __restrict__ out,
    float* __restrict__ ws, int usePre) {
  // 161,216 B static LDS (gfx950: 163,840 B available)
  __shared__ __align__(16) float hbuf[16640];  // h pair hi/lo [65][256]; later: codebook [128][129]
  __shared__ __align__(16) float obuf[16896];  // x-pair / attn-out pair + ex / f1 pair / head f32 scratch
  __shared__ __align__(16) float scr[6768];    // attention Qf/Kf/VT f32 (S overlays Qf/Kf) | VQ partials

  const int tid = threadIdx.x;
  const int b = blockIdx.x;
  const int lane = tid & 63, wave = tid >> 6;  // wave 0..15
  const int q4 = lane >> 4, cl = lane & 15;
  const f32x4 Z4 = {0.f, 0.f, 0.f, 0.f};
  _Float16* hH = (_Float16*)hbuf;
  _Float16* hL = hH + 65 * 256;
  const _Float16* WH = (const _Float16*)(ws + 1056);
  const _Float16* WL = WH + E_TOT;

  // ---------------- embed: h[0]=cls, h[1+r] = x[r] @ W_in^T + b_in + PE[r] ----------------
  {
    _Float16* xH = (_Float16*)obuf;
    _Float16* xL = xH + 64 * 256;  // pair pitch 256 (cols >=160 never read)
    for (int f = tid; f < SEQ * 160; f += NT) {
      int r = f / 160, c = f - r * 160;
      float v = (c < CIN) ? x[(size_t)b * (SEQ * CIN) + r * CIN + c] : 0.f;
      _Float16 h = (_Float16)v;
      int off = pidx(256, r, c);
      xH[off] = h;
      xL[off] = (_Float16)((v - (float)h) * LO_SCALE);
    }
    if (tid < DM) {  // row 0 = cls (t=0 -> identity swizzle)
      float v = cls_token[tid];
      _Float16 h = (_Float16)v;
      hH[tid] = h;
      hL[tid] = (_Float16)((v - (float)h) * LO_SCALE);
    }
    __syncthreads();
    for (int rg = 0; rg < 2; ++rg) {  // row-groups [0,32), [32,64); ot = wave
      f32x4 a1[1][2], a2[1][2];
#pragma unroll
      for (int tt = 0; tt < 2; ++tt) { a1[0][tt] = Z4; a2[0][tt] = Z4; }
      mfma_gw<2, 1, 0>(a1, a2, W_in, nullptr, nullptr, CIN, 0, 32, wave, 16,
                       xH + rg * 32 * 256, xL + rg * 32 * 256, 256, 32, 160,
                       CIN, lane);
#pragma unroll
      for (int tt = 0; tt < 2; ++tt) {
        int t = rg * 32 + 16 * tt + cl;  // 0..63
        int o = wave * 16 + q4 * 4;
        f32x4 v;
#pragma unroll
        for (int rgx = 0; rgx < 4; ++rgx) {
          int d = o + rgx;
          float div = expf(-(float)(d & ~1) * (9.210340371976184f / 256.0f));
          float ang = (float)t * div;
          float pe = (d & 1) ? cosf(ang) : sinf(ang);
          v[rgx] = a1[0][tt][rgx] + a2[0][tt][rgx] * LO_INV + b_in[d] + pe;
        }
        pair_store4(hH, hL, 256, t + 1, o, v);
      }
    }
  }
  __syncthreads();  // h ready before first qkv gemm

  // ---------------- transformer layers ----------------
  for (int li = 0; li < NL; ++li) {
    const float* Wqkv_l = Wqkv + (size_t)li * 768 * DM;
    const float* bqkv_l = bqkv + li * 768;
    const float* Wo_l = Wo + (size_t)li * DM * DM;
    const float* bo_l = bo + li * DM;
    const float* W1_l = W1 + (size_t)li * FFD * DM;
    const float* b1_l = b1 + li * FFD;
    const float* W2_l = W2 + (size_t)li * DM * FFD;
    const float* b2_l = b2 + li * DM;
    const _Float16* WqkvH_l = WH + (size_t)li * 768 * DM;
    const _Float16* WqkvL_l = WL + (size_t)li * 768 * DM;
    const _Float16* WoH_l = WH + OFF_WO + (size_t)li * DM * DM;
    const _Float16* WoL_l = WL + OFF_WO + (size_t)li * DM * DM;
    const _Float16* W1H_l = WH + OFF_W1 + (size_t)li * FFD * DM;
    const _Float16* W1L_l = WL + OFF_W1 + (size_t)li * FFD * DM;
    const _Float16* W2H_l = WH + OFF_W2 + (size_t)li * DM * FFD;
    const _Float16* W2L_l = WL + OFF_W2 + (size_t)li * DM * FFD;
    _Float16* oH = (_Float16*)obuf;          // attn-out pair [65][256]
    _Float16* oL = oH + 65 * 256;
    float* ex = obuf + 16640;                // 193 f32: q64, k64, scol, srow

    // ---- attention per head ----
    for (int hd = 0; hd < NH; ++hd) {
      float* Qf = scr;            // [64][36]
      float* Kf = scr + 2304;     // [64][36]
      float* VT = scr + 4608;     // [32][66] (col 64 = t=64 row of v)
      float* Sb = scr;            // [65][66] overlays Qf/Kf
      if (usePre)
        qkv_phase<2>(nullptr, WqkvH_l, WqkvL_l, bqkv_l, hd, hH, hL,
                     Qf, Kf, VT, ex, wave, lane);
      else
        qkv_phase<1>(Wqkv_l, nullptr, nullptr, bqkv_l, hd, hH, hL,
                     Qf, Kf, VT, ex, wave, lane);
      __syncthreads();  // (2) Q/K/VT ready
      // scores: every wave owns one 16x16 main tile (16 tiles); fringe
      // matvec tiles on waves 0-8.
      f32x4 sm1 = Z4, sm2 = Z4;
      {
        int rt = wave >> 2, ct = wave & 3;
        f16x8 bh, bl, ah, al;
        split8_f4(&Kf[(16 * ct + cl) * 36 + 8 * q4], bh, bl);
        split8_f4(&Qf[(16 * rt + cl) * 36 + 8 * q4], ah, al);
        sm1 = __builtin_amdgcn_mfma_f32_16x16x32_f16(ah, bh, sm1, 0, 0, 0);
        sm2 = __builtin_amdgcn_mfma_f32_16x16x32_f16(ah, bl, sm2, 0, 0, 0);
        sm2 = __builtin_amdgcn_mfma_f32_16x16x32_f16(al, bh, sm2, 0, 0, 0);
      }
      if (wave < 4) {
        // scol[t] = Q[t].k64 for tile wave: B row 0 = k64, D col 0
        int tt4 = wave;
        float vv[8];
#pragma unroll
        for (int j = 0; j < 8; ++j) {
          float v = ex[32 + 8 * q4 + j];
          vv[j] = (cl == 0) ? v : 0.f;
        }
        f16x8 kh, kl;
        split8_arr(vv, kh, kl);
        f16x8 qh, ql;
        split8_f4(&Qf[(16 * tt4 + cl) * 36 + 8 * q4], qh, ql);
        f32x4 c1 = Z4, c2 = Z4;
        c1 = __builtin_amdgcn_mfma_f32_16x16x32_f16(qh, kh, c1, 0, 0, 0);
        c2 = __builtin_amdgcn_mfma_f32_16x16x32_f16(qh, kl, c2, 0, 0, 0);
        c2 = __builtin_amdgcn_mfma_f32_16x16x32_f16(ql, kh, c2, 0, 0, 0);
        if (cl == 0) {
#pragma unroll
          for (int rg = 0; rg < 4; ++rg)
            ex[64 + 16 * tt4 + q4 * 4 + rg] = c1[rg] + c2[rg] * LO_INV;
        }
      } else if (wave < 8) {
        // srow[u] = q64.K[u] for tile wave-4: A row 0 = q64, D row 0
        int tt4 = wave - 4;
        float vv[8];
#pragma unroll
        for (int j = 0; j < 8; ++j) {
          float v = ex[8 * q4 + j];
          vv[j] = (cl == 0) ? v : 0.f;
        }
        f16x8 qh, ql;
        split8_arr(vv, qh, ql);
        f16x8 kh, kl;
        split8_f4(&Kf[(16 * tt4 + cl) * 36 + 8 * q4], kh, kl);
        f32x4 r1 = Z4, r2 = Z4;
        r1 = __builtin_amdgcn_mfma_f32_16x16x32_f16(qh, kh, r1, 0, 0, 0);
        r2 = __builtin_amdgcn_mfma_f32_16x16x32_f16(qh, kl, r2, 0, 0, 0);
        r2 = __builtin_amdgcn_mfma_f32_16x16x32_f16(ql, kh, r2, 0, 0, 0);
        if (q4 == 0) ex[128 + 16 * tt4 + cl] = r1[0] + r2[0] * LO_INV;
      } else if (wave == 8) {  // s64 = q64.k64
        float p = ex[lane & 31] * ex[32 + (lane & 31)];
        p = wave_bsum(p) * 0.5f;  // both halves duplicate
        if (lane == 0) ex[128 + 64] = p;
      }
      __syncthreads();  // (3) Q/K reads done; fringe written; S may overwrite
      {
        int rt = wave >> 2, ct = wave & 3;
#pragma unroll
        for (int rg = 0; rg < 4; ++rg)
          Sb[(rt * 16 + q4 * 4 + rg) * 66 + ct * 16 + cl] =
              sm1[rg] + sm2[rg] * LO_INV;
      }
      if (wave == 4) {
        Sb[lane * 66 + 64] = ex[64 + lane];
      } else if (wave == 5) {
        Sb[64 * 66 + lane] = ex[128 + lane];
        if (lane == 0) Sb[64 * 66 + 64] = ex[128 + 64];
      }
      __syncthreads();  // (4) S complete
      {
        const float sc = 0.17677669529663687f;  // 1/sqrt(32)
        for (int t = wave; t < 65; t += NW) {
          float s = Sb[t * 66 + lane] * sc;
          float s64 = Sb[t * 66 + 64] * sc;
          float m = fmaxf(wave_bmax(s), s64);
          float e = __expf(s - m), e64 = __expf(s64 - m);
          float inv = 1.0f / (wave_bsum(e) + e64);
          Sb[t * 66 + lane] = e * inv;
          if (lane == 0) Sb[t * 66 + 64] = e64 * inv;
        }
      }
      __syncthreads();  // (5) P ready
      if (wave < 8) {
        // P@V: 8 tiles (wave -> t-tile w>>1, d-tile w&1), swapped: D[d][t]
        int rt = wave >> 1, ct = wave & 1;
        f32x4 o1 = Z4, o2 = Z4;
#pragma unroll
        for (int kc = 0; kc < 64; kc += 32) {
          f16x8 ph, pl, vh, vl;
          split8_f2(&Sb[(16 * rt + cl) * 66 + kc + 8 * q4], ph, pl);
          split8_f2(&VT[(16 * ct + cl) * 66 + kc + 8 * q4], vh, vl);
          o1 = __builtin_amdgcn_mfma_f32_16x16x32_f16(vh, ph, o1, 0, 0, 0);
          o2 = __builtin_amdgcn_mfma_f32_16x16x32_f16(vh, pl, o2, 0, 0, 0);
          o2 = __builtin_amdgcn_mfma_f32_16x16x32_f16(vl, ph, o2, 0, 0, 0);
        }
        int t = rt * 16 + cl;       // 0..63
        float p64 = Sb[t * 66 + 64];
        int ob = ct * 16 + q4 * 4;
        f32x4 v;
#pragma unroll
        for (int rg = 0; rg < 4; ++rg) {
          int d = ob + rg;
          v[rg] = o1[rg] + o2[rg] * LO_INV + p64 * VT[d * 66 + 64];  // u=64 fixup
        }
        pair_store4(oH, oL, 256, t, hd * 32 + ob, v);
      } else {
        // O row t=64: waves 8-15, 4 d's each; lanes split u by 16-lane group
        int d = (wave - 8) * 4 + q4;  // 0..31
        float o = 0.f;
        for (int uu = cl; uu < 65; uu += 16)
          o += Sb[64 * 66 + uu] * VT[d * 66 + uu];
#pragma unroll
        for (int off = 8; off >= 1; off >>= 1) o += __shfl_xor(o, off, 64);
        if (cl == 0) {
          int c = hd * 32 + d;
          _Float16 h = (_Float16)o;
          int off2 = pidx(256, 64, c);  // 64&7=0 -> identity
          oH[off2] = h;
          oL[off2] = (_Float16)((o - (float)h) * LO_SCALE);
        }
      }
    }
    __syncthreads();  // o-pair complete

    // ---- proj + residual; LN1 ----
    if (usePre)
      proj_phase<2>(nullptr, WoH_l, WoL_l, bo_l, oH, oL, hH, hL, wave, lane);
    else
      proj_phase<1>(Wo_l, nullptr, nullptr, bo_l, oH, oL, hH, hL, wave, lane);
    __syncthreads();
    ln_rows_pair(hH, hL, ln1_g + li * DM, ln1_b + li * DM, wave, lane);
    __syncthreads();

    // ---- FF: T-split two-pass ----
    {
      _Float16* f1H = (_Float16*)obuf;
      _Float16* f1L = f1H + 33 * 512;
      if (usePre) {
        ff_pass0<2>(W1_l, b1_l, W2_l, b2_l, W1H_l, W1L_l, W2H_l, W2L_l,
                    hH, hL, f1H, f1L, wave, lane);
        __syncthreads();
        ff_pass1<2>(W1_l, b1_l, W2_l, b2_l, W1H_l, W1L_l, W2H_l, W2L_l,
                    hH, hL, f1H, f1L, wave, lane);
      } else {
        ff_pass0<1>(W1_l, b1_l, W2_l, b2_l, nullptr, nullptr, nullptr, nullptr,
                    hH, hL, f1H, f1L, wave, lane);
        __syncthreads();
        ff_pass1<1>(W1_l, b1_l, W2_l, b2_l, nullptr, nullptr, nullptr, nullptr,
                    hH, hL, f1H, f1L, wave, lane);
      }
    }
    __syncthreads();
    ln_rows_pair(hH, hL, ln2_g + li * DM, ln2_b + li * DM, wave, lane);
    __syncthreads();
  }

  // ---------------- head: lnf(cls) -> z_e -> VQ argmin -> decoder (exact fp32) ----------------
  if (tid < 64) {  // lnf on row 0 (t=0 -> identity swizzle) -> obuf[0..255]
    int c0 = 2 * lane, c1 = 128 + 2 * lane;
    float v0 = (float)hH[c0] + (float)hL[c0] * LO_INV;
    float v1 = (float)hH[c0 + 1] + (float)hL[c0 + 1] * LO_INV;
    float v2 = (float)hH[c1] + (float)hL[c1] * LO_INV;
    float v3 = (float)hH[c1 + 1] + (float)hL[c1 + 1] * LO_INV;
    float m = wave_bsum(v0 + v1 + v2 + v3) * (1.0f / 256.0f);
    float d0 = v0 - m, d1 = v1 - m, d2 = v2 - m, d3 = v3 - m;
    float var = wave_bsum(d0 * d0 + d1 * d1 + d2 * d2 + d3 * d3) * (1.0f / 256.0f);
    float rstd = 1.0f / sqrtf(var + 1e-5f);
    obuf[c0]     = d0 * rstd * lnf_g[c0]     + lnf_b[c0];
    obuf[c0 + 1] = d1 * rstd * lnf_g[c0 + 1] + lnf_b[c0 + 1];
    obuf[c1]     = d2 * rstd * lnf_g[c1]     + lnf_b[c1];
    obuf[c1 + 1] = d3 * rstd * lnf_g[c1 + 1] + lnf_b[c1 + 1];
  }
  __syncthreads();
  // z_e = lnf(cls) @ W_out^T + b_out -> obuf[256..384)
  for (int o = wave; o < ED; o += NW) {
    const float4 w4 = *(const float4*)&W_out[o * DM + lane * 4];
    const float4 c4 = *(const float4*)&obuf[lane * 4];
    float s = w4.x * c4.x + w4.y * c4.y + w4.z * c4.z + w4.w * c4.w;
    s = wave_bsum(s);
    if (lane == 0) obuf[256 + o] = s + b_out[o];
  }
  __syncthreads();

  // VQ argmin over |cb|^2 - 2 ze.cb (|ze|^2 constant); first-index tie-break
  float bestv = 3.4e38f;
  int bestk = 0;
  for (int ch = 0; ch < 8; ++ch) {
    __syncthreads();
    for (int f = tid; f < 128 * 128; f += NT) {  // stage cb chunk, rows padded to 129
      int r = f >> 7, c = f & 127;
      hbuf[r * 129 + c] = codebook[(size_t)(ch * 128 + r) * ED + c];
    }
    __syncthreads();
    {
      int kl = tid & 127, q = tid >> 7;  // q 0..7 (1024 threads)
      float part = 0.f;
#pragma unroll 4
      for (int jj = 0; jj < 16; ++jj) {
        int e = q * 16 + jj;
        float cv = hbuf[kl * 129 + e];
        part += cv * (cv - 2.0f * obuf[256 + e]);
      }
      scr[kl * 8 + q] = part;
    }
    __syncthreads();
    if (tid < 128) {
      float d2v = 0.f;
#pragma unroll
      for (int j = 0; j < 8; ++j) d2v += scr[tid * 8 + j];
      int kk = ch * 128 + tid;
      if (d2v < bestv) { bestv = d2v; bestk = kk; }  // ascending k per thread
    }
  }
  if (tid < 128) {
    scr[1024 + tid] = bestv;
    scr[1152 + tid] = __int_as_float(bestk);
  }
  __syncthreads();
  if (tid == 0) {
    float bv = 3.4e38f;
    int bk = 1 << 30;
    for (int j = 0; j < 128; ++j) {
      float v = scr[1024 + j];
      int kk = __float_as_int(scr[1152 + j]);
      if (v < bv || (v == bv && kk < bk)) { bv = v; bk = kk; }
    }
    scr[1300] = __int_as_float(bk);
    out[2 * NB + b] = (float)bk;  // indices output (as float value)
  }
  __syncthreads();
  const int bk = __float_as_int(scr[1300]);

  // z_q -> obuf[384..512); commitment + histogram
  if (tid < ED) {
    float zqv = codebook[(size_t)bk * ED + tid];
    obuf[384 + tid] = zqv;
    float df = zqv - obuf[256 + tid];
    float sq = wave_bsum(df * df);
    if ((tid & 63) == 0) atomicAdd(&ws[0], sq);
  }
  if (tid == 0) atomicAdd(&ws[1 + bk], 1.0f);
  __syncthreads();

  // decoder: d1 = zq @ Wd1^T + bd1 (256) -> LN -> gelu -> @Wd2^T (128) -> gelu -> @Wd3^T (2)
  for (int o = wave; o < DM; o += NW) {
    const float2 w2 = *(const float2*)&Wd1[o * ED + lane * 2];
    const float2 z2 = *(const float2*)&obuf[384 + lane * 2];
    float s = wave_bsum(w2.x * z2.x + w2.y * z2.y);
    if (lane == 0) obuf[512 + o] = s + bd1[o];
  }
  __syncthreads();
  if (tid < 64) {
    float v0 = obuf[512 + lane], v1 = obuf[512 + lane + 64];
    float v2 = obuf[512 + lane + 128], v3 = obuf[512 + lane + 192];
    float m = wave_bsum(v0 + v1 + v2 + v3) * (1.0f / 256.0f);
    float d0 = v0 - m, d1 = v1 - m, d2 = v2 - m, d3 = v3 - m;
    float var = wave_bsum(d0 * d0 + d1 * d1 + d2 * d2 + d3 * d3) * (1.0f / 256.0f);
    float rstd = 1.0f / sqrtf(var + 1e-5f);
    obuf[512 + lane]       = gelu_f(d0 * rstd * lnd_g[lane]       + lnd_b[lane]);
    obuf[512 + lane + 64]  = gelu_f(d1 * rstd * lnd_g[lane + 64]  + lnd_b[lane + 64]);
    obuf[512 + lane + 128] = gelu_f(d2 * rstd * lnd_g[lane + 128] + lnd_b[lane + 128]);
    obuf[512 + lane + 192] = gelu_f(d3 * rstd * lnd_g[lane + 192] + lnd_b[lane + 192]);
  }
  __syncthreads();
  for (int o = wave; o < ED; o += NW) {
    const float4 w4 = *(const float4*)&Wd2[o * DM + lane * 4];
    const float4 g4 = *(const float4*)&obuf[512 + lane * 4];
    float s = wave_bsum(w4.x * g4.x + w4.y * g4.y + w4.z * g4.z + w4.w * g4.w);
    if (lane == 0) obuf[768 + o] = gelu_f(s + bd2[o]);
  }
  __syncthreads();
  if (wave < 2) {
    const float2 w2 = *(const float2*)&Wd3[wave * ED + lane * 2];
    const float2 g2 = *(const float2*)&obuf[768 + lane * 2];
    float s = wave_bsum(w2.x * g2.x + w2.y * g2.y);
    if (lane == 0) out[b * 2 + wave] = s + bd3[wave];
  }
}

__global__ void vqvae_finish(const float* __restrict__ ws, float* __restrict__ out) {
  __shared__ float red[256];
  int tid = threadIdx.x;
  float part = 0.f;
  for (int k = tid; k < KCB; k += 256) {
    float p = ws[1 + k] * (1.0f / 2048.0f);
    part += p * logf(p + 1e-10f);
  }
  red[tid] = part;
  __syncthreads();
  for (int s = 128; s > 0; s >>= 1) {
    if (tid < s) red[tid] += red[tid + s];
    __syncthreads();
  }
  if (tid == 0) {
    out[2 * NB + NB]     = 0.1f * ws[0] * (1.0f / (2048.0f * 128.0f));  // commitment loss
    out[2 * NB + NB + 1] = expf(-red[0]);                               // perplexity
  }
}

extern "C" void kernel_launch(void* const* d_in, const int* in_sizes, int n_in,
                              void* d_out, int out_size, void* d_ws, size_t ws_size,
                              hipStream_t stream) {
  (void)in_sizes; (void)n_in; (void)out_size;
  const float* x         = (const float*)d_in[0];
  const float* W_in      = (const float*)d_in[1];
  const float* b_in      = (const float*)d_in[2];
  const float* cls_token = (const float*)d_in[3];
  const float* Wqkv      = (const float*)d_in[4];
  const float* bqkv      = (const float*)d_in[5];
  const float* Wo        = (const float*)d_in[6];
  const float* bo        = (const float*)d_in[7];
  const float* W1        = (const float*)d_in[8];
  const float* b1        = (const float*)d_in[9];
  const float* W2        = (const float*)d_in[10];
  const float* b2        = (const float*)d_in[11];
  const float* ln1_g     = (const float*)d_in[12];
  const float* ln1_b     = (const float*)d_in[13];
  const float* ln2_g     = (const float*)d_in[14];
  const float* ln2_b     = (const float*)d_in[15];
  const float* lnf_g     = (const float*)d_in[16];
  const float* lnf_b     = (const float*)d_in[17];
  const float* W_out     = (const float*)d_in[18];
  const float* b_out     = (const float*)d_in[19];
  const float* codebook  = (const float*)d_in[20];
  const float* Wd1       = (const float*)d_in[21];
  const float* bd1       = (const float*)d_in[22];
  const float* lnd_g     = (const float*)d_in[23];
  const float* lnd_b     = (const float*)d_in[24];
  const float* Wd2       = (const float*)d_in[25];
  const float* bd2       = (const float*)d_in[26];
  const float* Wd3       = (const float*)d_in[27];
  const float* bd3       = (const float*)d_in[28];
  float* out = (float*)d_out;
  float* ws = (float*)d_ws;

  const int usePre = (ws_size >= (size_t)WS_NEED) ? 1 : 0;

  hipLaunchKernelGGL(vqvae_zero, dim3(5), dim3(256), 0, stream, ws);
  if (usePre)
    hipLaunchKernelGGL(vqvae_prep, dim3(2048), dim3(512), 0, stream,
                       Wqkv, Wo, W1, W2, ws);
  hipLaunchKernelGGL(vqvae_main, dim3(NB), dim3(NT), 0, stream,
                     x, W_in, b_in, cls_token, Wqkv, bqkv, Wo, bo, W1, b1, W2, b2,
                     ln1_g, ln1_b, ln2_g, ln2_b, lnf_g, lnf_b, W_out, b_out,
                     codebook, Wd1, bd1, lnd_g, lnd_b, Wd2, bd2, Wd3, bd3, out,
                     ws, usePre);
  hipLaunchKernelGGL(vqvae_finish, dim3(1), dim3(256), 0, stream, ws, out);
}

// Round 10
// 6544.640 us; speedup vs baseline: 1.0062x; 1.0062x over previous
//
#include <hip/hip_runtime.h>
#include <math.h>

// Problem constants
#define NB   2048   // batch
#define SEQ  64
#define CIN  142
#define DM   256
#define NH   8
#define DHD  32
#define FFD  512
#define NL   3
#define ED   128
#define KCB  1024
#define TT   65     // SEQ+1 (cls prepended)
#define NT   1024   // threads per block (16 waves -> 4 waves/SIMD)
#define NW   16     // waves per block

// Preconverted-weights workspace layout (floats 0..1055 = header):
//   ws[0] commitment, ws[1..1024] histogram, pad to 1056.
//   PH = (_Float16*)(ws+1056): hi plane [E_TOT]; PL = PH + E_TOT: lo plane.
#define E_TOT    1572864
#define OFF_WO   589824
#define OFF_W1   786432
#define OFF_W2   1179648
#define WS_NEED  (4224 + 4 * E_TOT)  // bytes

typedef __attribute__((ext_vector_type(4))) float f32x4;
typedef __attribute__((ext_vector_type(8))) _Float16 f16x8;
typedef __attribute__((ext_vector_type(4))) _Float16 f16x4;
typedef __attribute__((ext_vector_type(2))) _Float16 f16x2;

// ---- split-fp16: x = hi + lo*2^-11, both fp16; lo pre-scaled by 2^11.
//   C = Whi*Ahi + (Whi*Alo' + Wlo'*Ahi) * 2^-11   (lo*lo ~2^-22, dropped)
// Activations live as hi/lo f16 pair arrays in LDS; weights preconverted to
// f16 pair planes in d_ws (fallback: in-loop split).
// R10: 16 waves (4/SIMD) with EVERY gemm sized for the measured 64-VGPR cap
// (allocator budgets ~2 WGs/CU irrespective of LDS: 512T->128, 1024T->64).
// R9's CIT=2 FF calls (acc 32 + frags ~80 live) spilled 1 GB/dispatch at the
// 64-reg cap; R10 converts them to two sequential CIT=1 calls (~55 live).
// All other shapes (TTN<=2, CIT=1) already fit.
#define LO_SCALE 2048.0f
#define LO_INV   (1.0f / 2048.0f)

__device__ __forceinline__ float gelu_f(float x) {
  return 0.5f * x * (1.0f + erff(x * 0.70710678118654752f));
}

__device__ __forceinline__ float wave_bsum(float v) {
#pragma unroll
  for (int off = 32; off >= 1; off >>= 1) v += __shfl_xor(v, off, 64);
  return v;
}
__device__ __forceinline__ float wave_bmax(float v) {
#pragma unroll
  for (int off = 32; off >= 1; off >>= 1) v = fmaxf(v, __shfl_xor(v, off, 64));
  return v;
}

// Swizzled pair-array index (pitch in halves, multiple of 64): 16B slots
// (8 halves) XORed by (row&7) -> rows spread over all 8 bank groups.
__device__ __forceinline__ int pidx(int pitch, int t, int c) {
  return t * pitch + ((((c >> 3) ^ (t & 7)) << 3) | (c & 7));
}

__device__ __forceinline__ void split4v(f32x4 v, f16x4& hi, f16x4& lo) {
#pragma unroll
  for (int j = 0; j < 4; ++j) {
    _Float16 h = (_Float16)v[j];
    hi[j] = h;
    lo[j] = (_Float16)((v[j] - (float)h) * LO_SCALE);
  }
}

__device__ __forceinline__ void pair_store4(_Float16* dH, _Float16* dL, int pitch,
                                            int t, int o, f32x4 v) {
  f16x4 hi, lo;
  split4v(v, hi, lo);
  int off = pidx(pitch, t, o);
  *(f16x4*)&dH[off] = hi;
  *(f16x4*)&dL[off] = lo;
}
__device__ __forceinline__ f32x4 pair_load4(const _Float16* dH, const _Float16* dL,
                                            int pitch, int t, int o) {
  int off = pidx(pitch, t, o);
  f16x4 hi = *(const f16x4*)&dH[off];
  f16x4 lo = *(const f16x4*)&dL[off];
  f32x4 v;
#pragma unroll
  for (int j = 0; j < 4; ++j) v[j] = (float)hi[j] + (float)lo[j] * LO_INV;
  return v;
}

// 8 f32 (array) -> split f16x8 pair
__device__ __forceinline__ void split8_arr(const float* vv, f16x8& hi, f16x8& lo) {
#pragma unroll
  for (int j = 0; j < 8; ++j) {
    _Float16 h = (_Float16)vv[j];
    hi[j] = h;
    lo[j] = (_Float16)((vv[j] - (float)h) * LO_SCALE);
  }
}
// 8 consecutive f32 (16B-aligned) -> split pair
__device__ __forceinline__ void split8_f4(const float* p, f16x8& hi, f16x8& lo) {
  float4 v0 = *(const float4*)p;
  float4 v1 = *(const float4*)(p + 4);
  float vv[8] = {v0.x, v0.y, v0.z, v0.w, v1.x, v1.y, v1.z, v1.w};
  split8_arr(vv, hi, lo);
}
// 8 consecutive f32 (8B-aligned) -> split pair
__device__ __forceinline__ void split8_f2(const float* p, f16x8& hi, f16x8& lo) {
  float vv[8];
#pragma unroll
  for (int j = 0; j < 4; ++j) {
    float2 v = *(const float2*)(p + 2 * j);
    vv[2 * j] = v.x;
    vv[2 * j + 1] = v.y;
  }
  split8_arr(vv, hi, lo);
}

// ---------- barrier-free MFMA GEMM: per-wave o-tiles, ot0 resolved by caller.
// C[T][O] += A[T][K] * W[O][K]^T. A: split-pair in LDS (swizzled, pitch
// apitch; base row multiple of 8). W: WMODE 0 = f32 guarded scalar (embed);
// 1 = f32 aligned reg-split; 2 = preconverted f16 pair planes.
// Wave's tiles: {ot0 + otstride*ci}; ot0 < 0 -> idle (wave-uniform).
// Operand-swapped MFMA: D[o_loc = (lane>>4)*4+reg][t = lane&15].
// R10 contract: TTN<=2, CIT=1 everywhere (fits the 64-VGPR cap at 1024T).
template <int TTN, int CIT, int WMODE>
__device__ __forceinline__ void mfma_gw(
    f32x4 (&acc1)[CIT][TTN], f32x4 (&acc2)[CIT][TTN],
    const float* __restrict__ Wg, const _Float16* __restrict__ WgH,
    const _Float16* __restrict__ WgL, int wld, int rbase, int rsel,
    int ot0, int otstride,
    const _Float16* aH, const _Float16* aL, int apitch, int tRows,
    int kdim, int kvalid, int lane) {
  if (ot0 < 0) return;
  const int q4 = lane >> 4, cl = lane & 15;
  int wrow[CIT];
#pragma unroll
  for (int ci = 0; ci < CIT; ++ci) {
    int r = (ot0 + otstride * ci) * 16 + cl;
    wrow[ci] = (rbase + (r & 31) + rsel * (r >> 5)) * wld;
  }
  f16x8 zf;
#pragma unroll
  for (int j = 0; j < 8; ++j) zf[j] = (_Float16)0.f;
#pragma unroll 1
  for (int kc = 0; kc < kdim; kc += 32) {
    f16x8 bh[CIT], bl[CIT];
#pragma unroll
    for (int ci = 0; ci < CIT; ++ci) {
      if (WMODE == 2) {
        int off = wrow[ci] + kc + 8 * q4;
        bh[ci] = *(const f16x8*)&WgH[off];
        bl[ci] = *(const f16x8*)&WgL[off];
      } else if (WMODE == 1) {
        split8_f4(Wg + wrow[ci] + kc + 8 * q4, bh[ci], bl[ci]);
      } else {  // embed: wld=142 unaligned + k tail guard
        const float* wp = Wg + wrow[ci] + kc + 8 * q4;
        int cb = kc + 8 * q4;
        float vv[8];
#pragma unroll
        for (int j = 0; j < 8; ++j) vv[j] = (cb + j < kvalid) ? wp[j] : 0.f;
        split8_arr(vv, bh[ci], bl[ci]);
      }
    }
#pragma unroll
    for (int tt = 0; tt < TTN; ++tt) {
      int t = 16 * tt + cl;
      f16x8 ah, al;
      if (t < tRows) {
        int off = t * apitch + (((((kc >> 3) + q4) ^ (t & 7))) << 3);
        ah = *(const f16x8*)&aH[off];
        al = *(const f16x8*)&aL[off];
      } else {
        ah = zf;
        al = zf;
      }
#pragma unroll
      for (int ci = 0; ci < CIT; ++ci) {
        acc1[ci][tt] = __builtin_amdgcn_mfma_f32_16x16x32_f16(bh[ci], ah, acc1[ci][tt], 0, 0, 0);
        acc2[ci][tt] = __builtin_amdgcn_mfma_f32_16x16x32_f16(bh[ci], al, acc2[ci][tt], 0, 0, 0);
        acc2[ci][tt] = __builtin_amdgcn_mfma_f32_16x16x32_f16(bl[ci], ah, acc2[ci][tt], 0, 0, 0);
      }
    }
  }
}

// qkv epilogue: write Q/K/VT (+t=64 extras) for o-tile ot, rows [base, base+tvalid)
__device__ __forceinline__ void qkv_epi2(const f32x4* a1, const f32x4* a2,
                                         int nt, int base, int tvalid, int ot,
                                         const float* __restrict__ bqkv_l, int hd,
                                         float* Qf, float* Kf, float* VT,
                                         float* ex, int lane) {
  const int q4 = lane >> 4, cl = lane & 15;
  for (int tt = 0; tt < nt; ++tt) {
    int tl = 16 * tt + cl;
    if (tl < tvalid) {
      int t = base + tl;
#pragma unroll
      for (int rg = 0; rg < 4; ++rg) {
        int c = ot * 16 + q4 * 4 + rg;  // 0..95
        int d = c & 31;
        float v = a1[tt][rg] + a2[tt][rg] * LO_INV +
                  bqkv_l[(c >> 5) * 256 + hd * 32 + d];
        if (c < 32)      { if (t < 64) Qf[t * 36 + d] = v; else ex[d] = v; }
        else if (c < 64) { if (t < 64) Kf[t * 36 + d] = v; else ex[32 + d] = v; }
        else             VT[d * 66 + t] = v;
      }
    }
  }
}

// proj epilogue: h += acc + bias; o-tile ot (16 cols), rows [base, base+tvalid)
__device__ __forceinline__ void proj_epi2(const f32x4* a1, const f32x4* a2,
                                          int nt, int base, int tvalid, int ot,
                                          const float* __restrict__ bo_l,
                                          _Float16* hH, _Float16* hL, int lane) {
  const int q4 = lane >> 4, cl = lane & 15;
  for (int tt = 0; tt < nt; ++tt) {
    int tl = 16 * tt + cl;
    if (tl < tvalid) {
      int t = base + tl;
      int o = ot * 16 + q4 * 4;
      f32x4 r = pair_load4(hH, hL, 256, t, o);
      float4 b4 = *(const float4*)&bo_l[o];
      float bb[4] = {b4.x, b4.y, b4.z, b4.w};
      f32x4 v;
#pragma unroll
      for (int rg = 0; rg < 4; ++rg)
        v[rg] = r[rg] + a1[tt][rg] + a2[tt][rg] * LO_INV + bb[rg];
      pair_store4(hH, hL, 256, t, o, v);
    }
  }
}

// qkv phase: 18 tasks over 16 waves (12 big TTN=2 + 6 small TTN=1; waves
// 12,13 take a second small). Gemms touch only h + W; barrier (1) separates
// prev head's Sb/VT reads from the scr epilogue writes.
template <int WM>
__device__ __forceinline__ void qkv_phase(
    const float* __restrict__ Wq, const _Float16* __restrict__ WqH,
    const _Float16* __restrict__ WqL, const float* __restrict__ bqkv_l, int hd,
    const _Float16* hH, const _Float16* hL,
    float* Qf, float* Kf, float* VT, float* ex, int wave, int lane) {
  const f32x4 Z4 = {0.f, 0.f, 0.f, 0.f};
  f32x4 b1a[1][2], b2a[1][2], s1a[1][1], s2a[1][1], s1b[1][1], s2b[1][1];
#pragma unroll
  for (int tt = 0; tt < 2; ++tt) { b1a[0][tt] = Z4; b2a[0][tt] = Z4; }
  s1a[0][0] = Z4; s2a[0][0] = Z4; s1b[0][0] = Z4; s2b[0][0] = Z4;
  const int bigot = (wave < 12) ? (wave >> 1) : -1;
  const int bigbase = (wave & 1) * 32;
  const int sot1 = (wave >= 12) ? (wave - 12) : -1;
  const int sot2 = (wave == 12) ? 4 : ((wave == 13) ? 5 : -1);
  mfma_gw<2, 1, WM>(b1a, b2a, Wq, WqH, WqL, DM, hd * 32, 256, bigot, 16,
                    hH + bigbase * 256, hL + bigbase * 256, 256, 32, DM, DM,
                    lane);
  mfma_gw<1, 1, WM>(s1a, s2a, Wq, WqH, WqL, DM, hd * 32, 256, sot1, 16,
                    hH + 64 * 256, hL + 64 * 256, 256, 1, DM, DM, lane);
  mfma_gw<1, 1, WM>(s1b, s2b, Wq, WqH, WqL, DM, hd * 32, 256, sot2, 16,
                    hH + 64 * 256, hL + 64 * 256, 256, 1, DM, DM, lane);
  __syncthreads();  // (1) prev head's Sb/VT reads done; scr writable
  if (bigot >= 0)
    qkv_epi2(&b1a[0][0], &b2a[0][0], 2, bigbase, 32, bigot, bqkv_l, hd,
             Qf, Kf, VT, ex, lane);
  if (sot1 >= 0)
    qkv_epi2(&s1a[0][0], &s2a[0][0], 1, 64, 1, sot1, bqkv_l, hd,
             Qf, Kf, VT, ex, lane);
  if (sot2 >= 0)
    qkv_epi2(&s1b[0][0], &s2b[0][0], 1, 64, 1, sot2, bqkv_l, hd,
             Qf, Kf, VT, ex, lane);
}

// proj: wave = o-tile (16 tiles x 16 cols); rows {32,32,1}; K=256 each.
template <int WM>
__device__ __forceinline__ void proj_phase(
    const float* __restrict__ Wo_l, const _Float16* __restrict__ WoH,
    const _Float16* __restrict__ WoL, const float* __restrict__ bo_l,
    const _Float16* oH, const _Float16* oL,
    _Float16* hH, _Float16* hL, int wave, int lane) {
  const f32x4 Z4 = {0.f, 0.f, 0.f, 0.f};
  {
    f32x4 a1[1][2], a2[1][2];
#pragma unroll
    for (int tt = 0; tt < 2; ++tt) { a1[0][tt] = Z4; a2[0][tt] = Z4; }
    mfma_gw<2, 1, WM>(a1, a2, Wo_l, WoH, WoL, DM, 0, 32, wave, 16,
                      oH, oL, 256, 32, DM, DM, lane);
    proj_epi2(&a1[0][0], &a2[0][0], 2, 0, 32, wave, bo_l, hH, hL, lane);
  }
  {
    f32x4 a1[1][2], a2[1][2];
#pragma unroll
    for (int tt = 0; tt < 2; ++tt) { a1[0][tt] = Z4; a2[0][tt] = Z4; }
    mfma_gw<2, 1, WM>(a1, a2, Wo_l, WoH, WoL, DM, 0, 32, wave, 16,
                      oH + 32 * 256, oL + 32 * 256, 256, 32, DM, DM, lane);
    proj_epi2(&a1[0][0], &a2[0][0], 2, 32, 32, wave, bo_l, hH, hL, lane);
  }
  {
    f32x4 a1[1][1], a2[1][1];
    a1[0][0] = Z4; a2[0][0] = Z4;
    mfma_gw<1, 1, WM>(a1, a2, Wo_l, WoH, WoL, DM, 0, 32, wave, 16,
                      oH + 64 * 256, oL + 64 * 256, 256, 1, DM, DM, lane);
    proj_epi2(&a1[0][0], &a2[0][0], 1, 64, 1, wave, bo_l, hH, hL, lane);
  }
}

// FF pass 0: rows [0,32). FF1: 32 o-tiles, two sequential CIT=1 calls
// (tiles wave and wave+16); FF2: 16 o-tiles, one CIT=1 call.
template <int WM>
__device__ __forceinline__ void ff_pass0(
    const float* __restrict__ W1_l, const float* __restrict__ b1_l,
    const float* __restrict__ W2_l, const float* __restrict__ b2_l,
    const _Float16* __restrict__ W1H, const _Float16* __restrict__ W1L,
    const _Float16* __restrict__ W2H, const _Float16* __restrict__ W2L,
    _Float16* hH, _Float16* hL, _Float16* f1H, _Float16* f1L,
    int wave, int lane) {
  const int q4 = lane >> 4, cl = lane & 15;
  const f32x4 Z4 = {0.f, 0.f, 0.f, 0.f};
  for (int ci = 0; ci < 2; ++ci) {  // o-tile = wave + 16*ci
    f32x4 a1[1][2], a2[1][2];
#pragma unroll
    for (int tt = 0; tt < 2; ++tt) { a1[0][tt] = Z4; a2[0][tt] = Z4; }
    mfma_gw<2, 1, WM>(a1, a2, W1_l, W1H, W1L, DM, 0, 32, wave + 16 * ci, 16,
                      hH, hL, 256, 32, DM, DM, lane);
#pragma unroll
    for (int tt = 0; tt < 2; ++tt) {
      int t = 16 * tt + cl;
      int m = (wave + 16 * ci) * 16 + q4 * 4;
      float4 b4 = *(const float4*)&b1_l[m];
      float bb[4] = {b4.x, b4.y, b4.z, b4.w};
      f32x4 v;
#pragma unroll
      for (int rg = 0; rg < 4; ++rg)
        v[rg] = gelu_f(a1[0][tt][rg] + a2[0][tt][rg] * LO_INV + bb[rg]);
      pair_store4(f1H, f1L, 512, t, m, v);
    }
  }
  __syncthreads();  // f1 ready
  {
    f32x4 a1[1][2], a2[1][2];
#pragma unroll
    for (int tt = 0; tt < 2; ++tt) { a1[0][tt] = Z4; a2[0][tt] = Z4; }
    mfma_gw<2, 1, WM>(a1, a2, W2_l, W2H, W2L, FFD, 0, 32, wave, 16,
                      f1H, f1L, 512, 32, FFD, FFD, lane);
#pragma unroll
    for (int tt = 0; tt < 2; ++tt) {
      int t = 16 * tt + cl;
      int o = wave * 16 + q4 * 4;
      f32x4 r = pair_load4(hH, hL, 256, t, o);
      float4 b4 = *(const float4*)&b2_l[o];
      float bb[4] = {b4.x, b4.y, b4.z, b4.w};
      f32x4 v;
#pragma unroll
      for (int rg = 0; rg < 4; ++rg)
        v[rg] = r[rg] + a1[0][tt][rg] + a2[0][tt][rg] * LO_INV + bb[rg];
      pair_store4(hH, hL, 256, t, o, v);
    }
  }
}

// FF pass 1: rows [32,65) (f1 local rows 0..32). All CIT=1 calls.
template <int WM>
__device__ __forceinline__ void ff_pass1(
    const float* __restrict__ W1_l, const float* __restrict__ b1_l,
    const float* __restrict__ W2_l, const float* __restrict__ b2_l,
    const _Float16* __restrict__ W1H, const _Float16* __restrict__ W1L,
    const _Float16* __restrict__ W2H, const _Float16* __restrict__ W2L,
    _Float16* hH, _Float16* hL, _Float16* f1H, _Float16* f1L,
    int wave, int lane) {
  const int q4 = lane >> 4, cl = lane & 15;
  const f32x4 Z4 = {0.f, 0.f, 0.f, 0.f};
  for (int ci = 0; ci < 2; ++ci) {  // FF1 rows 32-63: o-tile = wave + 16*ci
    f32x4 a1[1][2], a2[1][2];
#pragma unroll
    for (int tt = 0; tt < 2; ++tt) { a1[0][tt] = Z4; a2[0][tt] = Z4; }
    mfma_gw<2, 1, WM>(a1, a2, W1_l, W1H, W1L, DM, 0, 32, wave + 16 * ci, 16,
                      hH + 32 * 256, hL + 32 * 256, 256, 32, DM, DM, lane);
#pragma unroll
    for (int tt = 0; tt < 2; ++tt) {
      int tl = 16 * tt + cl;  // f1 local row 0..31
      int m = (wave + 16 * ci) * 16 + q4 * 4;
      float4 b4 = *(const float4*)&b1_l[m];
      float bb[4] = {b4.x, b4.y, b4.z, b4.w};
      f32x4 v;
#pragma unroll
      for (int rg = 0; rg < 4; ++rg)
        v[rg] = gelu_f(a1[0][tt][rg] + a2[0][tt][rg] * LO_INV + bb[rg]);
      pair_store4(f1H, f1L, 512, tl, m, v);
    }
  }
  for (int ci = 0; ci < 2; ++ci) {  // FF1 row 64 -> f1 local row 32
    f32x4 c1[1][1], c2[1][1];
    c1[0][0] = Z4; c2[0][0] = Z4;
    mfma_gw<1, 1, WM>(c1, c2, W1_l, W1H, W1L, DM, 0, 32, wave + 16 * ci, 16,
                      hH + 64 * 256, hL + 64 * 256, 256, 1, DM, DM, lane);
    if (cl < 1) {
      int m = (wave + 16 * ci) * 16 + q4 * 4;
      float4 b4 = *(const float4*)&b1_l[m];
      float bb[4] = {b4.x, b4.y, b4.z, b4.w};
      f32x4 v;
#pragma unroll
      for (int rg = 0; rg < 4; ++rg)
        v[rg] = gelu_f(c1[0][0][rg] + c2[0][0][rg] * LO_INV + bb[rg]);
      pair_store4(f1H, f1L, 512, 32, m, v);
    }
  }
  __syncthreads();  // f1 ready
  {
    f32x4 a1[1][2], a2[1][2];
#pragma unroll
    for (int tt = 0; tt < 2; ++tt) { a1[0][tt] = Z4; a2[0][tt] = Z4; }
    mfma_gw<2, 1, WM>(a1, a2, W2_l, W2H, W2L, FFD, 0, 32, wave, 16,
                      f1H, f1L, 512, 32, FFD, FFD, lane);
#pragma unroll
    for (int tt = 0; tt < 2; ++tt) {
      int t = 32 + 16 * tt + cl;
      int o = wave * 16 + q4 * 4;
      f32x4 r = pair_load4(hH, hL, 256, t, o);
      float4 b4 = *(const float4*)&b2_l[o];
      float bb[4] = {b4.x, b4.y, b4.z, b4.w};
      f32x4 v;
#pragma unroll
      for (int rg = 0; rg < 4; ++rg)
        v[rg] = r[rg] + a1[0][tt][rg] + a2[0][tt][rg] * LO_INV + bb[rg];
      pair_store4(hH, hL, 256, t, o, v);
    }
    f32x4 c1[1][1], c2[1][1];
    c1[0][0] = Z4; c2[0][0] = Z4;
    mfma_gw<1, 1, WM>(c1, c2, W2_l, W2H, W2L, FFD, 0, 32, wave, 16,
                      f1H + 32 * 512, f1L + 32 * 512, 512, 1, FFD, FFD, lane);
    if (cl < 1) {
      int o = wave * 16 + q4 * 4;
      f32x4 r = pair_load4(hH, hL, 256, 64, o);
      float4 b4 = *(const float4*)&b2_l[o];
      float bb[4] = {b4.x, b4.y, b4.z, b4.w};
      f32x4 v;
#pragma unroll
      for (int rg = 0; rg < 4; ++rg)
        v[rg] = r[rg] + c1[0][0][rg] + c2[0][0][rg] * LO_INV + bb[rg];
      pair_store4(hH, hL, 256, 64, o, v);
    }
  }
}

// LayerNorm on the pair-stored residual stream
__device__ __forceinline__ void ln_rows_pair(_Float16* hH, _Float16* hL,
                                             const float* g, const float* be,
                                             int wave, int lane) {
  for (int t = wave; t < TT; t += NW) {
    int c0 = 2 * lane, c1 = 128 + 2 * lane;
    int o0 = pidx(256, t, c0), o1 = pidx(256, t, c1);
    f16x2 h0 = *(f16x2*)&hH[o0], l0 = *(f16x2*)&hL[o0];
    f16x2 h1 = *(f16x2*)&hH[o1], l1 = *(f16x2*)&hL[o1];
    float v0 = (float)h0[0] + (float)l0[0] * LO_INV;
    float v1 = (float)h0[1] + (float)l0[1] * LO_INV;
    float v2 = (float)h1[0] + (float)l1[0] * LO_INV;
    float v3 = (float)h1[1] + (float)l1[1] * LO_INV;
    float m = wave_bsum(v0 + v1 + v2 + v3) * (1.0f / 256.0f);
    float d0 = v0 - m, d1 = v1 - m, d2 = v2 - m, d3 = v3 - m;
    float var = wave_bsum(d0 * d0 + d1 * d1 + d2 * d2 + d3 * d3) * (1.0f / 256.0f);
    float rstd = 1.0f / sqrtf(var + 1e-5f);
    float2 g0 = *(const float2*)&g[c0], g1 = *(const float2*)&g[c1];
    float2 b0 = *(const float2*)&be[c0], b1 = *(const float2*)&be[c1];
    float r0 = d0 * rstd * g0.x + b0.x;
    float r1 = d1 * rstd * g0.y + b0.y;
    float r2 = d2 * rstd * g1.x + b1.x;
    float r3 = d3 * rstd * g1.y + b1.y;
    f16x2 nh0, nl0, nh1, nl1;
    nh0[0] = (_Float16)r0; nl0[0] = (_Float16)((r0 - (float)nh0[0]) * LO_SCALE);
    nh0[1] = (_Float16)r1; nl0[1] = (_Float16)((r1 - (float)nh0[1]) * LO_SCALE);
    nh1[0] = (_Float16)r2; nl1[0] = (_Float16)((r2 - (float)nh1[0]) * LO_SCALE);
    nh1[1] = (_Float16)r3; nl1[1] = (_Float16)((r3 - (float)nh1[1]) * LO_SCALE);
    *(f16x2*)&hH[o0] = nh0; *(f16x2*)&hL[o0] = nl0;
    *(f16x2*)&hH[o1] = nh1; *(f16x2*)&hL[o1] = nl1;
  }
}

__global__ void vqvae_zero(float* __restrict__ ws) {
  int i = blockIdx.x * blockDim.x + threadIdx.x;
  if (i < 1025) ws[i] = 0.f;
}

// Preconvert layer weights into split-f16 planes in ws (once per dispatch).
__global__ void vqvae_prep(const float* __restrict__ Wqkv,
                           const float* __restrict__ Wo,
                           const float* __restrict__ W1,
                           const float* __restrict__ W2,
                           float* __restrict__ ws) {
  _Float16* PH = (_Float16*)(ws + 1056);
  _Float16* PL = PH + E_TOT;
  for (int i = blockIdx.x * blockDim.x + threadIdx.x; i < E_TOT;
       i += gridDim.x * blockDim.x) {
    float v;
    if (i < OFF_WO)      v = Wqkv[i];
    else if (i < OFF_W1) v = Wo[i - OFF_WO];
    else if (i < OFF_W2) v = W1[i - OFF_W1];
    else                 v = W2[i - OFF_W2];
    _Float16 h = (_Float16)v;
    PH[i] = h;
    PL[i] = (_Float16)((v - (float)h) * LO_SCALE);
  }
}

// LDS (161,216 B) -> 1 block/CU; 16 waves/block = 4 waves/SIMD.
__global__ __attribute__((amdgpu_flat_work_group_size(1024, 1024), amdgpu_waves_per_eu(4, 4)))
void vqvae_main(
    const float* __restrict__ x, const float* __restrict__ W_in,
    const float* __restrict__ b_in, const float* __restrict__ cls_token,
    const float* __restrict__ Wqkv, const float* __restrict__ bqkv,
    const float* __restrict__ Wo, const float* __restrict__ bo,
    const float* __restrict__ W1, const float* __restrict__ b1,
    const float* __restrict__ W2, const float* __restrict__ b2,
    const float* __restrict__ ln1_g, const float* __restrict__ ln1_b,
    const float* __restrict__ ln2_g, const float* __restrict__ ln2_b,
    const float* __restrict__ lnf_g, const float* __restrict__ lnf_b,
    const float* __restrict__ W_out, const float* __restrict__ b_out,
    const float* __restrict__ codebook, const float* __restrict__ Wd1,
    const float* __restrict__ bd1, const float* __restrict__ lnd_g,
    const float* __restrict__ lnd_b, const float* __restrict__ Wd2,
    const float* __restrict__ bd2, const float* __restrict__ Wd3,
    const float* __restrict__ bd3, float* __restrict__ out,
    float* __restrict__ ws, int usePre) {
  // 161,216 B static LDS (gfx950: 163,840 B available)
  __shared__ __align__(16) float hbuf[16640];  // h pair hi/lo [65][256]; later: codebook [128][129]
  __shared__ __align__(16) float obuf[16896];  // x-pair / attn-out pair + ex / f1 pair / head f32 scratch
  __shared__ __align__(16) float scr[6768];    // attention Qf/Kf/VT f32 (S overlays Qf/Kf) | VQ partials

  const int tid = threadIdx.x;
  const int b = blockIdx.x;
  const int lane = tid & 63, wave = tid >> 6;  // wave 0..15
  const int q4 = lane >> 4, cl = lane & 15;
  const f32x4 Z4 = {0.f, 0.f, 0.f, 0.f};
  _Float16* hH = (_Float16*)hbuf;
  _Float16* hL = hH + 65 * 256;
  const _Float16* WH = (const _Float16*)(ws + 1056);
  const _Float16* WL = WH + E_TOT;

  // ---------------- embed: h[0]=cls, h[1+r] = x[r] @ W_in^T + b_in + PE[r] ----------------
  {
    _Float16* xH = (_Float16*)obuf;
    _Float16* xL = xH + 64 * 256;  // pair pitch 256 (cols >=160 never read)
    for (int f = tid; f < SEQ * 160; f += NT) {
      int r = f / 160, c = f - r * 160;
      float v = (c < CIN) ? x[(size_t)b * (SEQ * CIN) + r * CIN + c] : 0.f;
      _Float16 h = (_Float16)v;
      int off = pidx(256, r, c);
      xH[off] = h;
      xL[off] = (_Float16)((v - (float)h) * LO_SCALE);
    }
    if (tid < DM) {  // row 0 = cls (t=0 -> identity swizzle)
      float v = cls_token[tid];
      _Float16 h = (_Float16)v;
      hH[tid] = h;
      hL[tid] = (_Float16)((v - (float)h) * LO_SCALE);
    }
    __syncthreads();
    for (int rg = 0; rg < 2; ++rg) {  // row-groups [0,32), [32,64); ot = wave
      f32x4 a1[1][2], a2[1][2];
#pragma unroll
      for (int tt = 0; tt < 2; ++tt) { a1[0][tt] = Z4; a2[0][tt] = Z4; }
      mfma_gw<2, 1, 0>(a1, a2, W_in, nullptr, nullptr, CIN, 0, 32, wave, 16,
                       xH + rg * 32 * 256, xL + rg * 32 * 256, 256, 32, 160,
                       CIN, lane);
#pragma unroll
      for (int tt = 0; tt < 2; ++tt) {
        int t = rg * 32 + 16 * tt + cl;  // 0..63
        int o = wave * 16 + q4 * 4;
        f32x4 v;
#pragma unroll
        for (int rgx = 0; rgx < 4; ++rgx) {
          int d = o + rgx;
          float div = expf(-(float)(d & ~1) * (9.210340371976184f / 256.0f));
          float ang = (float)t * div;
          float pe = (d & 1) ? cosf(ang) : sinf(ang);
          v[rgx] = a1[0][tt][rgx] + a2[0][tt][rgx] * LO_INV + b_in[d] + pe;
        }
        pair_store4(hH, hL, 256, t + 1, o, v);
      }
    }
  }
  __syncthreads();  // h ready before first qkv gemm

  // ---------------- transformer layers ----------------
  for (int li = 0; li < NL; ++li) {
    const float* Wqkv_l = Wqkv + (size_t)li * 768 * DM;
    const float* bqkv_l = bqkv + li * 768;
    const float* Wo_l = Wo + (size_t)li * DM * DM;
    const float* bo_l = bo + li * DM;
    const float* W1_l = W1 + (size_t)li * FFD * DM;
    const float* b1_l = b1 + li * FFD;
    const float* W2_l = W2 + (size_t)li * DM * FFD;
    const float* b2_l = b2 + li * DM;
    const _Float16* WqkvH_l = WH + (size_t)li * 768 * DM;
    const _Float16* WqkvL_l = WL + (size_t)li * 768 * DM;
    const _Float16* WoH_l = WH + OFF_WO + (size_t)li * DM * DM;
    const _Float16* WoL_l = WL + OFF_WO + (size_t)li * DM * DM;
    const _Float16* W1H_l = WH + OFF_W1 + (size_t)li * FFD * DM;
    const _Float16* W1L_l = WL + OFF_W1 + (size_t)li * FFD * DM;
    const _Float16* W2H_l = WH + OFF_W2 + (size_t)li * DM * FFD;
    const _Float16* W2L_l = WL + OFF_W2 + (size_t)li * DM * FFD;
    _Float16* oH = (_Float16*)obuf;          // attn-out pair [65][256]
    _Float16* oL = oH + 65 * 256;
    float* ex = obuf + 16640;                // 193 f32: q64, k64, scol, srow

    // ---- attention per head ----
    for (int hd = 0; hd < NH; ++hd) {
      float* Qf = scr;            // [64][36]
      float* Kf = scr + 2304;     // [64][36]
      float* VT = scr + 4608;     // [32][66] (col 64 = t=64 row of v)
      float* Sb = scr;            // [65][66] overlays Qf/Kf
      if (usePre)
        qkv_phase<2>(nullptr, WqkvH_l, WqkvL_l, bqkv_l, hd, hH, hL,
                     Qf, Kf, VT, ex, wave, lane);
      else
        qkv_phase<1>(Wqkv_l, nullptr, nullptr, bqkv_l, hd, hH, hL,
                     Qf, Kf, VT, ex, wave, lane);
      __syncthreads();  // (2) Q/K/VT ready
      // scores: every wave owns one 16x16 main tile (16 tiles); fringe
      // matvec tiles on waves 0-8.
      f32x4 sm1 = Z4, sm2 = Z4;
      {
        int rt = wave >> 2, ct = wave & 3;
        f16x8 bh, bl, ah, al;
        split8_f4(&Kf[(16 * ct + cl) * 36 + 8 * q4], bh, bl);
        split8_f4(&Qf[(16 * rt + cl) * 36 + 8 * q4], ah, al);
        sm1 = __builtin_amdgcn_mfma_f32_16x16x32_f16(ah, bh, sm1, 0, 0, 0);
        sm2 = __builtin_amdgcn_mfma_f32_16x16x32_f16(ah, bl, sm2, 0, 0, 0);
        sm2 = __builtin_amdgcn_mfma_f32_16x16x32_f16(al, bh, sm2, 0, 0, 0);
      }
      if (wave < 4) {
        // scol[t] = Q[t].k64 for tile wave: B row 0 = k64, D col 0
        int tt4 = wave;
        float vv[8];
#pragma unroll
        for (int j = 0; j < 8; ++j) {
          float v = ex[32 + 8 * q4 + j];
          vv[j] = (cl == 0) ? v : 0.f;
        }
        f16x8 kh, kl;
        split8_arr(vv, kh, kl);
        f16x8 qh, ql;
        split8_f4(&Qf[(16 * tt4 + cl) * 36 + 8 * q4], qh, ql);
        f32x4 c1 = Z4, c2 = Z4;
        c1 = __builtin_amdgcn_mfma_f32_16x16x32_f16(qh, kh, c1, 0, 0, 0);
        c2 = __builtin_amdgcn_mfma_f32_16x16x32_f16(qh, kl, c2, 0, 0, 0);
        c2 = __builtin_amdgcn_mfma_f32_16x16x32_f16(ql, kh, c2, 0, 0, 0);
        if (cl == 0) {
#pragma unroll
          for (int rg = 0; rg < 4; ++rg)
            ex[64 + 16 * tt4 + q4 * 4 + rg] = c1[rg] + c2[rg] * LO_INV;
        }
      } else if (wave < 8) {
        // srow[u] = q64.K[u] for tile wave-4: A row 0 = q64, D row 0
        int tt4 = wave - 4;
        float vv[8];
#pragma unroll
        for (int j = 0; j < 8; ++j) {
          float v = ex[8 * q4 + j];
          vv[j] = (cl == 0) ? v : 0.f;
        }
        f16x8 qh, ql;
        split8_arr(vv, qh, ql);
        f16x8 kh, kl;
        split8_f4(&Kf[(16 * tt4 + cl) * 36 + 8 * q4], kh, kl);
        f32x4 r1 = Z4, r2 = Z4;
        r1 = __builtin_amdgcn_mfma_f32_16x16x32_f16(qh, kh, r1, 0, 0, 0);
        r2 = __builtin_amdgcn_mfma_f32_16x16x32_f16(qh, kl, r2, 0, 0, 0);
        r2 = __builtin_amdgcn_mfma_f32_16x16x32_f16(ql, kh, r2, 0, 0, 0);
        if (q4 == 0) ex[128 + 16 * tt4 + cl] = r1[0] + r2[0] * LO_INV;
      } else if (wave == 8) {  // s64 = q64.k64
        float p = ex[lane & 31] * ex[32 + (lane & 31)];
        p = wave_bsum(p) * 0.5f;  // both halves duplicate
        if (lane == 0) ex[128 + 64] = p;
      }
      __syncthreads();  // (3) Q/K reads done; fringe written; S may overwrite
      {
        int rt = wave >> 2, ct = wave & 3;
#pragma unroll
        for (int rg = 0; rg < 4; ++rg)
          Sb[(rt * 16 + q4 * 4 + rg) * 66 + ct * 16 + cl] =
              sm1[rg] + sm2[rg] * LO_INV;
      }
      if (wave == 4) {
        Sb[lane * 66 + 64] = ex[64 + lane];
      } else if (wave == 5) {
        Sb[64 * 66 + lane] = ex[128 + lane];
        if (lane == 0) Sb[64 * 66 + 64] = ex[128 + 64];
      }
      __syncthreads();  // (4) S complete
      {
        const float sc = 0.17677669529663687f;  // 1/sqrt(32)
        for (int t = wave; t < 65; t += NW) {
          float s = Sb[t * 66 + lane] * sc;
          float s64 = Sb[t * 66 + 64] * sc;
          float m = fmaxf(wave_bmax(s), s64);
          float e = __expf(s - m), e64 = __expf(s64 - m);
          float inv = 1.0f / (wave_bsum(e) + e64);
          Sb[t * 66 + lane] = e * inv;
          if (lane == 0) Sb[t * 66 + 64] = e64 * inv;
        }
      }
      __syncthreads();  // (5) P ready
      if (wave < 8) {
        // P@V: 8 tiles (wave -> t-tile w>>1, d-tile w&1), swapped: D[d][t]
        int rt = wave >> 1, ct = wave & 1;
        f32x4 o1 = Z4, o2 = Z4;
#pragma unroll
        for (int kc = 0; kc < 64; kc += 32) {
          f16x8 ph, pl, vh, vl;
          split8_f2(&Sb[(16 * rt + cl) * 66 + kc + 8 * q4], ph, pl);
          split8_f2(&VT[(16 * ct + cl) * 66 + kc + 8 * q4], vh, vl);
          o1 = __builtin_amdgcn_mfma_f32_16x16x32_f16(vh, ph, o1, 0, 0, 0);
          o2 = __builtin_amdgcn_mfma_f32_16x16x32_f16(vh, pl, o2, 0, 0, 0);
          o2 = __builtin_amdgcn_mfma_f32_16x16x32_f16(vl, ph, o2, 0, 0, 0);
        }
        int t = rt * 16 + cl;       // 0..63
        float p64 = Sb[t * 66 + 64];
        int ob = ct * 16 + q4 * 4;
        f32x4 v;
#pragma unroll
        for (int rg = 0; rg < 4; ++rg) {
          int d = ob + rg;
          v[rg] = o1[rg] + o2[rg] * LO_INV + p64 * VT[d * 66 + 64];  // u=64 fixup
        }
        pair_store4(oH, oL, 256, t, hd * 32 + ob, v);
      } else {
        // O row t=64: waves 8-15, 4 d's each; lanes split u by 16-lane group
        int d = (wave - 8) * 4 + q4;  // 0..31
        float o = 0.f;
        for (int uu = cl; uu < 65; uu += 16)
          o += Sb[64 * 66 + uu] * VT[d * 66 + uu];
#pragma unroll
        for (int off = 8; off >= 1; off >>= 1) o += __shfl_xor(o, off, 64);
        if (cl == 0) {
          int c = hd * 32 + d;
          _Float16 h = (_Float16)o;
          int off2 = pidx(256, 64, c);  // 64&7=0 -> identity
          oH[off2] = h;
          oL[off2] = (_Float16)((o - (float)h) * LO_SCALE);
        }
      }
    }
    __syncthreads();  // o-pair complete

    // ---- proj + residual; LN1 ----
    if (usePre)
      proj_phase<2>(nullptr, WoH_l, WoL_l, bo_l, oH, oL, hH, hL, wave, lane);
    else
      proj_phase<1>(Wo_l, nullptr, nullptr, bo_l, oH, oL, hH, hL, wave, lane);
    __syncthreads();
    ln_rows_pair(hH, hL, ln1_g + li * DM, ln1_b + li * DM, wave, lane);
    __syncthreads();

    // ---- FF: T-split two-pass ----
    {
      _Float16* f1H = (_Float16*)obuf;
      _Float16* f1L = f1H + 33 * 512;
      if (usePre) {
        ff_pass0<2>(W1_l, b1_l, W2_l, b2_l, W1H_l, W1L_l, W2H_l, W2L_l,
                    hH, hL, f1H, f1L, wave, lane);
        __syncthreads();
        ff_pass1<2>(W1_l, b1_l, W2_l, b2_l, W1H_l, W1L_l, W2H_l, W2L_l,
                    hH, hL, f1H, f1L, wave, lane);
      } else {
        ff_pass0<1>(W1_l, b1_l, W2_l, b2_l, nullptr, nullptr, nullptr, nullptr,
                    hH, hL, f1H, f1L, wave, lane);
        __syncthreads();
        ff_pass1<1>(W1_l, b1_l, W2_l, b2_l, nullptr, nullptr, nullptr, nullptr,
                    hH, hL, f1H, f1L, wave, lane);
      }
    }
    __syncthreads();
    ln_rows_pair(hH, hL, ln2_g + li * DM, ln2_b + li * DM, wave, lane);
    __syncthreads();
  }

  // ---------------- head: lnf(cls) -> z_e -> VQ argmin -> decoder (exact fp32) ----------------
  if (tid < 64) {  // lnf on row 0 (t=0 -> identity swizzle) -> obuf[0..255]
    int c0 = 2 * lane, c1 = 128 + 2 * lane;
    float v0 = (float)hH[c0] + (float)hL[c0] * LO_INV;
    float v1 = (float)hH[c0 + 1] + (float)hL[c0 + 1] * LO_INV;
    float v2 = (float)hH[c1] + (float)hL[c1] * LO_INV;
    float v3 = (float)hH[c1 + 1] + (float)hL[c1 + 1] * LO_INV;
    float m = wave_bsum(v0 + v1 + v2 + v3) * (1.0f / 256.0f);
    float d0 = v0 - m, d1 = v1 - m, d2 = v2 - m, d3 = v3 - m;
    float var = wave_bsum(d0 * d0 + d1 * d1 + d2 * d2 + d3 * d3) * (1.0f / 256.0f);
    float rstd = 1.0f / sqrtf(var + 1e-5f);
    obuf[c0]     = d0 * rstd * lnf_g[c0]     + lnf_b[c0];
    obuf[c0 + 1] = d1 * rstd * lnf_g[c0 + 1] + lnf_b[c0 + 1];
    obuf[c1]     = d2 * rstd * lnf_g[c1]     + lnf_b[c1];
    obuf[c1 + 1] = d3 * rstd * lnf_g[c1 + 1] + lnf_b[c1 + 1];
  }
  __syncthreads();
  // z_e = lnf(cls) @ W_out^T + b_out -> obuf[256..384)
  for (int o = wave; o < ED; o += NW) {
    const float4 w4 = *(const float4*)&W_out[o * DM + lane * 4];
    const float4 c4 = *(const float4*)&obuf[lane * 4];
    float s = w4.x * c4.x + w4.y * c4.y + w4.z * c4.z + w4.w * c4.w;
    s = wave_bsum(s);
    if (lane == 0) obuf[256 + o] = s + b_out[o];
  }
  __syncthreads();

  // VQ argmin over |cb|^2 - 2 ze.cb (|ze|^2 constant); first-index tie-break
  float bestv = 3.4e38f;
  int bestk = 0;
  for (int ch = 0; ch < 8; ++ch) {
    __syncthreads();
    for (int f = tid; f < 128 * 128; f += NT) {  // stage cb chunk, rows padded to 129
      int r = f >> 7, c = f & 127;
      hbuf[r * 129 + c] = codebook[(size_t)(ch * 128 + r) * ED + c];
    }
    __syncthreads();
    {
      int kl = tid & 127, q = tid >> 7;  // q 0..7 (1024 threads)
      float part = 0.f;
#pragma unroll 4
      for (int jj = 0; jj < 16; ++jj) {
        int e = q * 16 + jj;
        float cv = hbuf[kl * 129 + e];
        part += cv * (cv - 2.0f * obuf[256 + e]);
      }
      scr[kl * 8 + q] = part;
    }
    __syncthreads();
    if (tid < 128) {
      float d2v = 0.f;
#pragma unroll
      for (int j = 0; j < 8; ++j) d2v += scr[tid * 8 + j];
      int kk = ch * 128 + tid;
      if (d2v < bestv) { bestv = d2v; bestk = kk; }  // ascending k per thread
    }
  }
  if (tid < 128) {
    scr[1024 + tid] = bestv;
    scr[1152 + tid] = __int_as_float(bestk);
  }
  __syncthreads();
  if (tid == 0) {
    float bv = 3.4e38f;
    int bk = 1 << 30;
    for (int j = 0; j < 128; ++j) {
      float v = scr[1024 + j];
      int kk = __float_as_int(scr[1152 + j]);
      if (v < bv || (v == bv && kk < bk)) { bv = v; bk = kk; }
    }
    scr[1300] = __int_as_float(bk);
    out[2 * NB + b] = (float)bk;  // indices output (as float value)
  }
  __syncthreads();
  const int bk = __float_as_int(scr[1300]);

  // z_q -> obuf[384..512); commitment + histogram
  if (tid < ED) {
    float zqv = codebook[(size_t)bk * ED + tid];
    obuf[384 + tid] = zqv;
    float df = zqv - obuf[256 + tid];
    float sq = wave_bsum(df * df);
    if ((tid & 63) == 0) atomicAdd(&ws[0], sq);
  }
  if (tid == 0) atomicAdd(&ws[1 + bk], 1.0f);
  __syncthreads();

  // decoder: d1 = zq @ Wd1^T + bd1 (256) -> LN -> gelu -> @Wd2^T (128) -> gelu -> @Wd3^T (2)
  for (int o = wave; o < DM; o += NW) {
    const float2 w2 = *(const float2*)&Wd1[o * ED + lane * 2];
    const float2 z2 = *(const float2*)&obuf[384 + lane * 2];
    float s = wave_bsum(w2.x * z2.x + w2.y * z2.y);
    if (lane == 0) obuf[512 + o] = s + bd1[o];
  }
  __syncthreads();
  if (tid < 64) {
    float v0 = obuf[512 + lane], v1 = obuf[512 + lane + 64];
    float v2 = obuf[512 + lane + 128], v3 = obuf[512 + lane + 192];
    float m = wave_bsum(v0 + v1 + v2 + v3) * (1.0f / 256.0f);
    float d0 = v0 - m, d1 = v1 - m, d2 = v2 - m, d3 = v3 - m;
    float var = wave_bsum(d0 * d0 + d1 * d1 + d2 * d2 + d3 * d3) * (1.0f / 256.0f);
    float rstd = 1.0f / sqrtf(var + 1e-5f);
    obuf[512 + lane]       = gelu_f(d0 * rstd * lnd_g[lane]       + lnd_b[lane]);
    obuf[512 + lane + 64]  = gelu_f(d1 * rstd * lnd_g[lane + 64]  + lnd_b[lane + 64]);
    obuf[512 + lane + 128] = gelu_f(d2 * rstd * lnd_g[lane + 128] + lnd_b[lane + 128]);
    obuf[512 + lane + 192] = gelu_f(d3 * rstd * lnd_g[lane + 192] + lnd_b[lane + 192]);
  }
  __syncthreads();
  for (int o = wave; o < ED; o += NW) {
    const float4 w4 = *(const float4*)&Wd2[o * DM + lane * 4];
    const float4 g4 = *(const float4*)&obuf[512 + lane * 4];
    float s = wave_bsum(w4.x * g4.x + w4.y * g4.y + w4.z * g4.z + w4.w * g4.w);
    if (lane == 0) obuf[768 + o] = gelu_f(s + bd2[o]);
  }
  __syncthreads();
  if (wave < 2) {
    const float2 w2 = *(const float2*)&Wd3[wave * ED + lane * 2];
    const float2 g2 = *(const float2*)&obuf[768 + lane * 2];
    float s = wave_bsum(w2.x * g2.x + w2.y * g2.y);
    if (lane == 0) out[b * 2 + wave] = s + bd3[wave];
  }
}

__global__ void vqvae_finish(const float* __restrict__ ws, float* __restrict__ out) {
  __shared__ float red[256];
  int tid = threadIdx.x;
  float part = 0.f;
  for (int k = tid; k < KCB; k += 256) {
    float p = ws[1 + k] * (1.0f / 2048.0f);
    part += p * logf(p + 1e-10f);
  }
  red[tid] = part;
  __syncthreads();
  for (int s = 128; s > 0; s >>= 1) {
    if (tid < s) red[tid] += red[tid + s];
    __syncthreads();
  }
  if (tid == 0) {
    out[2 * NB + NB]     = 0.1f * ws[0] * (1.0f / (2048.0f * 128.0f));  // commitment loss
    out[2 * NB + NB + 1] = expf(-red[0]);                               // perplexity
  }
}

extern "C" void kernel_launch(void* const* d_in, const int* in_sizes, int n_in,
                              void* d_out, int out_size, void* d_ws, size_t ws_size,
                              hipStream_t stream) {
  (void)in_sizes; (void)n_in; (void)out_size;
  const float* x         = (const float*)d_in[0];
  const float* W_in      = (const float*)d_in[1];
  const float* b_in      = (const float*)d_in[2];
  const float* cls_token = (const float*)d_in[3];
  const float* Wqkv      = (const float*)d_in[4];
  const float* bqkv      = (const float*)d_in[5];
  const float* Wo        = (const float*)d_in[6];
  const float* bo        = (const float*)d_in[7];
  const float* W1        = (const float*)d_in[8];
  const float* b1        = (const float*)d_in[9];
  const float* W2        = (const float*)d_in[10];
  const float* b2        = (const float*)d_in[11];
  const float* ln1_g     = (const float*)d_in[12];
  const float* ln1_b     = (const float*)d_in[13];
  const float* ln2_g     = (const float*)d_in[14];
  const float* ln2_b     = (const float*)d_in[15];
  const float* lnf_g     = (const float*)d_in[16];
  const float* lnf_b     = (const float*)d_in[17];
  const float* W_out     = (const float*)d_in[18];
  const float* b_out     = (const float*)d_in[19];
  const float* codebook  = (const float*)d_in[20];
  const float* Wd1       = (const float*)d_in[21];
  const float* bd1       = (const float*)d_in[22];
  const float* lnd_g     = (const float*)d_in[23];
  const float* lnd_b     = (const float*)d_in[24];
  const float* Wd2       = (const float*)d_in[25];
  const float* bd2       = (const float*)d_in[26];
  const float* Wd3       = (const float*)d_in[27];
  const float* bd3       = (const float*)d_in[28];
  float* out = (float*)d_out;
  float* ws = (float*)d_ws;

  const int usePre = (ws_size >= (size_t)WS_NEED) ? 1 : 0;

  hipLaunchKernelGGL(vqvae_zero, dim3(5), dim3(256), 0, stream, ws);
  if (usePre)
    hipLaunchKernelGGL(vqvae_prep, dim3(2048), dim3(512), 0, stream,
                       Wqkv, Wo, W1, W2, ws);
  hipLaunchKernelGGL(vqvae_main, dim3(NB), dim3(NT), 0, stream,
                     x, W_in, b_in, cls_token, Wqkv, bqkv, Wo, bo, W1, b1, W2, b2,
                     ln1_g, ln1_b, ln2_g, ln2_b, lnf_g, lnf_b, W_out, b_out,
                     codebook, Wd1, bd1, lnd_g, lnd_b, Wd2, bd2, Wd3, bd3, out,
                     ws, usePre);
  hipLaunchKernelGGL(vqvae_finish, dim3(1), dim3(256), 0, stream, ws, out);
}

// Round 11
// 5243.554 us; speedup vs baseline: 1.2559x; 1.2481x over previous
//
#include <hip/hip_runtime.h>
#include <math.h>

// Problem constants
#define NB   2048   // batch
#define SEQ  64
#define CIN  142
#define DM   256
#define NH   8
#define DHD  32
#define FFD  512
#define NL   3
#define ED   128
#define KCB  1024
#define TT   65     // SEQ+1 (cls prepended)
#define NT   512    // threads per block

// Preconverted-weights workspace layout (floats 0..1055 = header):
//   ws[0] commitment, ws[1..1024] histogram, pad to 1056.
//   PH = (_Float16*)(ws+1056): hi plane [E_TOT]; PL = PH + E_TOT: lo plane.
#define E_TOT    1572864
#define OFF_WO   589824
#define OFF_W1   786432
#define OFF_W2   1179648
#define WS_NEED  (4224 + 4 * E_TOT)  // bytes

typedef __attribute__((ext_vector_type(4))) float f32x4;
typedef __attribute__((ext_vector_type(8))) _Float16 f16x8;
typedef __attribute__((ext_vector_type(4))) _Float16 f16x4;
typedef __attribute__((ext_vector_type(2))) _Float16 f16x2;

// ---- split-fp16: x = hi + lo*2^-11, both fp16; lo pre-scaled by 2^11.
//   C = Whi*Ahi + (Whi*Alo' + Wlo'*Ahi) * 2^-11   (lo*lo ~2^-22, dropped)
// Activations live as hi/lo f16 pair arrays in LDS; weights preconverted to
// f16 pair planes in d_ws (fallback: in-loop split).
// R11: RESTORE of the measured optimum (R6, 5291 us). The R6-R10 sweep
// mapped the envelope: 512T->128 VGPR cap, 1024T->64 (attrs don't move it);
// LDS 161KB -> 1 block/CU. Split-fp16 gemm needs ~100+ live regs for
// latency-covering ILP -> only the 512T/128 envelope works; within it,
// TTN=5 (spill 102MB, 5.29ms) > TTN=3 (5.82) > TTN=2 (clean, 7.03):
// ILP dominates spill. 16-wave arm: 64-reg cap spills 1+GB (6.5ms both
// shapes). This file = R6 verbatim.
#define LO_SCALE 2048.0f
#define LO_INV   (1.0f / 2048.0f)

__device__ __forceinline__ float gelu_f(float x) {
  return 0.5f * x * (1.0f + erff(x * 0.70710678118654752f));
}

__device__ __forceinline__ float wave_bsum(float v) {
#pragma unroll
  for (int off = 32; off >= 1; off >>= 1) v += __shfl_xor(v, off, 64);
  return v;
}
__device__ __forceinline__ float wave_bmax(float v) {
#pragma unroll
  for (int off = 32; off >= 1; off >>= 1) v = fmaxf(v, __shfl_xor(v, off, 64));
  return v;
}

// Swizzled pair-array index (pitch in halves, multiple of 64): 16B slots
// (8 halves) XORed by (row&7) -> rows spread over all 8 bank groups.
__device__ __forceinline__ int pidx(int pitch, int t, int c) {
  return t * pitch + ((((c >> 3) ^ (t & 7)) << 3) | (c & 7));
}

__device__ __forceinline__ void split4v(f32x4 v, f16x4& hi, f16x4& lo) {
#pragma unroll
  for (int j = 0; j < 4; ++j) {
    _Float16 h = (_Float16)v[j];
    hi[j] = h;
    lo[j] = (_Float16)((v[j] - (float)h) * LO_SCALE);
  }
}

__device__ __forceinline__ void pair_store4(_Float16* dH, _Float16* dL, int pitch,
                                            int t, int o, f32x4 v) {
  f16x4 hi, lo;
  split4v(v, hi, lo);
  int off = pidx(pitch, t, o);
  *(f16x4*)&dH[off] = hi;
  *(f16x4*)&dL[off] = lo;
}
__device__ __forceinline__ f32x4 pair_load4(const _Float16* dH, const _Float16* dL,
                                            int pitch, int t, int o) {
  int off = pidx(pitch, t, o);
  f16x4 hi = *(const f16x4*)&dH[off];
  f16x4 lo = *(const f16x4*)&dL[off];
  f32x4 v;
#pragma unroll
  for (int j = 0; j < 4; ++j) v[j] = (float)hi[j] + (float)lo[j] * LO_INV;
  return v;
}

// 8 f32 (array) -> split f16x8 pair
__device__ __forceinline__ void split8_arr(const float* vv, f16x8& hi, f16x8& lo) {
#pragma unroll
  for (int j = 0; j < 8; ++j) {
    _Float16 h = (_Float16)vv[j];
    hi[j] = h;
    lo[j] = (_Float16)((vv[j] - (float)h) * LO_SCALE);
  }
}
// 8 consecutive f32 (16B-aligned) -> split pair
__device__ __forceinline__ void split8_f4(const float* p, f16x8& hi, f16x8& lo) {
  float4 v0 = *(const float4*)p;
  float4 v1 = *(const float4*)(p + 4);
  float vv[8] = {v0.x, v0.y, v0.z, v0.w, v1.x, v1.y, v1.z, v1.w};
  split8_arr(vv, hi, lo);
}
// 8 consecutive f32 (8B-aligned) -> split pair
__device__ __forceinline__ void split8_f2(const float* p, f16x8& hi, f16x8& lo) {
  float vv[8];
#pragma unroll
  for (int j = 0; j < 4; ++j) {
    float2 v = *(const float2*)(p + 2 * j);
    vv[2 * j] = v.x;
    vv[2 * j + 1] = v.y;
  }
  split8_arr(vv, hi, lo);
}

// ---------- barrier-free MFMA GEMM: C[T][O] += A[T][K] * W[O][K]^T ----------
// A: split-pair in LDS (swizzled, pitch apitch); one b128 per half per K=32.
// W: WMODE 0 = f32 global guarded scalar (embed); 1 = f32 aligned, reg-split;
//    2 = preconverted f16 pair planes, direct b128 loads.
// Per kc: load B for all ci (<=16 regs), then STREAM A per row-tile
// (8 regs) straight into its MFMAs. Operand-swapped MFMA:
// D[o_loc = (lane>>4)*4+reg][t = lane&15].
template <int TTN, int CIT, bool GUARDO, int WMODE>
__device__ __forceinline__ void mfma_gemm2(
    f32x4 (&acc1)[CIT][TTN], f32x4 (&acc2)[CIT][TTN],
    const float* __restrict__ Wg, const _Float16* __restrict__ WgH,
    const _Float16* __restrict__ WgL, int wld, int rbase, int rsel, int otiles,
    const _Float16* aH, const _Float16* aL, int apitch, int tRows,
    int kdim, int kvalid, int wave, int lane) {
  const int q4 = lane >> 4, cl = lane & 15;
  if (GUARDO && wave >= otiles) return;  // wave-uniform skip
  int wrow[CIT];
  bool oval[CIT];
#pragma unroll
  for (int ci = 0; ci < CIT; ++ci) {
    int ot = wave + 8 * ci;
    oval[ci] = !GUARDO || (ot < otiles);
    int r = ot * 16 + cl;
    int grow = rbase + (r & 31) + rsel * (r >> 5);
    wrow[ci] = grow * wld;
  }
  f16x8 zf;
#pragma unroll
  for (int j = 0; j < 8; ++j) zf[j] = (_Float16)0.f;
#pragma unroll 1
  for (int kc = 0; kc < kdim; kc += 32) {
    f16x8 bh[CIT], bl[CIT];
#pragma unroll
    for (int ci = 0; ci < CIT; ++ci) {
      if (oval[ci]) {
        if (WMODE == 2) {
          int off = wrow[ci] + kc + 8 * q4;
          bh[ci] = *(const f16x8*)&WgH[off];
          bl[ci] = *(const f16x8*)&WgL[off];
        } else if (WMODE == 1) {
          split8_f4(Wg + wrow[ci] + kc + 8 * q4, bh[ci], bl[ci]);
        } else {  // embed: wld=142 unaligned + k tail guard
          const float* wp = Wg + wrow[ci] + kc + 8 * q4;
          int cb = kc + 8 * q4;
          float vv[8];
#pragma unroll
          for (int j = 0; j < 8; ++j) vv[j] = (cb + j < kvalid) ? wp[j] : 0.f;
          split8_arr(vv, bh[ci], bl[ci]);
        }
      } else {
        bh[ci] = zf;
        bl[ci] = zf;
      }
    }
#pragma unroll
    for (int tt = 0; tt < TTN; ++tt) {
      int t = 16 * tt + cl;
      f16x8 ah, al;
      if (t < tRows) {
        int off = t * apitch + (((((kc >> 3) + q4) ^ (t & 7))) << 3);
        ah = *(const f16x8*)&aH[off];
        al = *(const f16x8*)&aL[off];
      } else {
        ah = zf;
        al = zf;
      }
#pragma unroll
      for (int ci = 0; ci < CIT; ++ci) {
        if (oval[ci]) {
          acc1[ci][tt] = __builtin_amdgcn_mfma_f32_16x16x32_f16(bh[ci], ah, acc1[ci][tt], 0, 0, 0);
          acc2[ci][tt] = __builtin_amdgcn_mfma_f32_16x16x32_f16(bh[ci], al, acc2[ci][tt], 0, 0, 0);
          acc2[ci][tt] = __builtin_amdgcn_mfma_f32_16x16x32_f16(bl[ci], ah, acc2[ci][tt], 0, 0, 0);
        }
      }
    }
  }
}

// LayerNorm on the pair-stored residual stream (reconstruct -> LN -> re-split)
__device__ __forceinline__ void ln_rows_pair(_Float16* hH, _Float16* hL,
                                             const float* g, const float* be,
                                             int wave, int lane) {
  for (int t = wave; t < TT; t += 8) {
    int c0 = 2 * lane, c1 = 128 + 2 * lane;
    int o0 = pidx(256, t, c0), o1 = pidx(256, t, c1);
    f16x2 h0 = *(f16x2*)&hH[o0], l0 = *(f16x2*)&hL[o0];
    f16x2 h1 = *(f16x2*)&hH[o1], l1 = *(f16x2*)&hL[o1];
    float v0 = (float)h0[0] + (float)l0[0] * LO_INV;
    float v1 = (float)h0[1] + (float)l0[1] * LO_INV;
    float v2 = (float)h1[0] + (float)l1[0] * LO_INV;
    float v3 = (float)h1[1] + (float)l1[1] * LO_INV;
    float m = wave_bsum(v0 + v1 + v2 + v3) * (1.0f / 256.0f);
    float d0 = v0 - m, d1 = v1 - m, d2 = v2 - m, d3 = v3 - m;
    float var = wave_bsum(d0 * d0 + d1 * d1 + d2 * d2 + d3 * d3) * (1.0f / 256.0f);
    float rstd = 1.0f / sqrtf(var + 1e-5f);
    float2 g0 = *(const float2*)&g[c0], g1 = *(const float2*)&g[c1];
    float2 b0 = *(const float2*)&be[c0], b1 = *(const float2*)&be[c1];
    float r0 = d0 * rstd * g0.x + b0.x;
    float r1 = d1 * rstd * g0.y + b0.y;
    float r2 = d2 * rstd * g1.x + b1.x;
    float r3 = d3 * rstd * g1.y + b1.y;
    f16x2 nh0, nl0, nh1, nl1;
    nh0[0] = (_Float16)r0; nl0[0] = (_Float16)((r0 - (float)nh0[0]) * LO_SCALE);
    nh0[1] = (_Float16)r1; nl0[1] = (_Float16)((r1 - (float)nh0[1]) * LO_SCALE);
    nh1[0] = (_Float16)r2; nl1[0] = (_Float16)((r2 - (float)nh1[0]) * LO_SCALE);
    nh1[1] = (_Float16)r3; nl1[1] = (_Float16)((r3 - (float)nh1[1]) * LO_SCALE);
    *(f16x2*)&hH[o0] = nh0; *(f16x2*)&hL[o0] = nl0;
    *(f16x2*)&hH[o1] = nh1; *(f16x2*)&hL[o1] = nl1;
  }
}

// FF pass for rows [r0, r0+nr): f1 = gelu(h@W1^T+b1) -> pair; h += f1@W2^T+b2
template <int RTF, int WM>
__device__ __forceinline__ void ff_block(int r0, int nr,
                                         const float* __restrict__ W1_l,
                                         const float* __restrict__ b1_l,
                                         const float* __restrict__ W2_l,
                                         const float* __restrict__ b2_l,
                                         const _Float16* __restrict__ W1H,
                                         const _Float16* __restrict__ W1L,
                                         const _Float16* __restrict__ W2H,
                                         const _Float16* __restrict__ W2L,
                                         _Float16* hH, _Float16* hL,
                                         _Float16* f1H, _Float16* f1L,
                                         int wave, int lane) {
  const int q4 = lane >> 4, cl = lane & 15;
  const f32x4 Z4 = {0.f, 0.f, 0.f, 0.f};
  for (int half = 0; half < 2; ++half) {
    f32x4 a1[2][RTF], a2[2][RTF];
#pragma unroll
    for (int ci = 0; ci < 2; ++ci)
#pragma unroll
      for (int tt = 0; tt < RTF; ++tt) { a1[ci][tt] = Z4; a2[ci][tt] = Z4; }
    mfma_gemm2<RTF, 2, false, WM>(a1, a2, W1_l, W1H, W1L, DM, half * 256, 32, 16,
                                  hH + r0 * 256, hL + r0 * 256, 256, nr,
                                  DM, DM, wave, lane);
#pragma unroll
    for (int ci = 0; ci < 2; ++ci)
#pragma unroll
      for (int tt = 0; tt < RTF; ++tt) {
        int t = 16 * tt + cl;
        if (t < nr) {
          int m = half * 256 + (wave + 8 * ci) * 16 + q4 * 4;
          float4 b4 = *(const float4*)&b1_l[m];
          float bb[4] = {b4.x, b4.y, b4.z, b4.w};
          f32x4 v;
#pragma unroll
          for (int rg = 0; rg < 4; ++rg)
            v[rg] = gelu_f(a1[ci][tt][rg] + a2[ci][tt][rg] * LO_INV + bb[rg]);
          pair_store4(f1H, f1L, 512, t, m, v);
        }
      }
  }
  __syncthreads();  // f1 ready
  {
    f32x4 a1[2][RTF], a2[2][RTF];
#pragma unroll
    for (int ci = 0; ci < 2; ++ci)
#pragma unroll
      for (int tt = 0; tt < RTF; ++tt) { a1[ci][tt] = Z4; a2[ci][tt] = Z4; }
    mfma_gemm2<RTF, 2, false, WM>(a1, a2, W2_l, W2H, W2L, FFD, 0, 32, 16,
                                  f1H, f1L, 512, nr, FFD, FFD, wave, lane);
#pragma unroll
    for (int ci = 0; ci < 2; ++ci)
#pragma unroll
      for (int tt = 0; tt < RTF; ++tt) {
        int t = 16 * tt + cl;
        if (t < nr) {
          int o = (wave + 8 * ci) * 16 + q4 * 4;
          f32x4 r = pair_load4(hH, hL, 256, r0 + t, o);
          float4 b4 = *(const float4*)&b2_l[o];
          float bb[4] = {b4.x, b4.y, b4.z, b4.w};
          f32x4 v;
#pragma unroll
          for (int rg = 0; rg < 4; ++rg)
            v[rg] = r[rg] + a1[ci][tt][rg] + a2[ci][tt][rg] * LO_INV + bb[rg];
          pair_store4(hH, hL, 256, r0 + t, o, v);
        }
      }
  }
}

__global__ void vqvae_zero(float* __restrict__ ws) {
  int i = blockIdx.x * blockDim.x + threadIdx.x;
  if (i < 1025) ws[i] = 0.f;
}

// Preconvert layer weights into split-f16 planes in ws (once per dispatch).
__global__ void vqvae_prep(const float* __restrict__ Wqkv,
                           const float* __restrict__ Wo,
                           const float* __restrict__ W1,
                           const float* __restrict__ W2,
                           float* __restrict__ ws) {
  _Float16* PH = (_Float16*)(ws + 1056);
  _Float16* PL = PH + E_TOT;
  for (int i = blockIdx.x * blockDim.x + threadIdx.x; i < E_TOT;
       i += gridDim.x * blockDim.x) {
    float v;
    if (i < OFF_WO)      v = Wqkv[i];
    else if (i < OFF_W1) v = Wo[i - OFF_WO];
    else if (i < OFF_W2) v = W1[i - OFF_W1];
    else                 v = W2[i - OFF_W2];
    _Float16 h = (_Float16)v;
    PH[i] = h;
    PL[i] = (_Float16)((v - (float)h) * LO_SCALE);
  }
}

// LDS (161,216 B) limits to 1 block/CU = 8 waves = 2 waves/SIMD.
__global__ __attribute__((amdgpu_flat_work_group_size(512, 512), amdgpu_waves_per_eu(2, 2)))
void vqvae_main(
    const float* __restrict__ x, const float* __restrict__ W_in,
    const float* __restrict__ b_in, const float* __restrict__ cls_token,
    const float* __restrict__ Wqkv, const float* __restrict__ bqkv,
    const float* __restrict__ Wo, const float* __restrict__ bo,
    const float* __restrict__ W1, const float* __restrict__ b1,
    const float* __restrict__ W2, const float* __restrict__ b2,
    const float* __restrict__ ln1_g, const float* __restrict__ ln1_b,
    const float* __restrict__ ln2_g, const float* __restrict__ ln2_b,
    const float* __restrict__ lnf_g, const float* __restrict__ lnf_b,
    const float* __restrict__ W_out, const float* __restrict__ b_out,
    const float* __restrict__ codebook, const float* __restrict__ Wd1,
    const float* __restrict__ bd1, const float* __restrict__ lnd_g,
    const float* __restrict__ lnd_b, const float* __restrict__ Wd2,
    const float* __restrict__ bd2, const float* __restrict__ Wd3,
    const float* __restrict__ bd3, float* __restrict__ out,
    float* __restrict__ ws, int usePre) {
  // 161,216 B static LDS (gfx950: 163,840 B available)
  __shared__ __align__(16) float hbuf[16640];  // h pair hi/lo [65][256]; later: codebook [128][129]
  __shared__ __align__(16) float obuf[16896];  // x-pair / attn-out pair + ex / f1 pair / head f32 scratch
  __shared__ __align__(16) float scr[6768];    // attention Qf/Kf/VT f32 (S overlays Qf/Kf) | VQ partials

  const int tid = threadIdx.x;
  const int b = blockIdx.x;
  const int lane = tid & 63, wave = tid >> 6;
  const int q4 = lane >> 4, cl = lane & 15;
  const f32x4 Z4 = {0.f, 0.f, 0.f, 0.f};
  _Float16* hH = (_Float16*)hbuf;
  _Float16* hL = hH + 65 * 256;
  const _Float16* WH = (const _Float16*)(ws + 1056);
  const _Float16* WL = WH + E_TOT;

  // ---------------- embed: h[0]=cls, h[1+r] = x[r] @ W_in^T + b_in + PE[r] ----------------
  {
    _Float16* xH = (_Float16*)obuf;
    _Float16* xL = xH + 64 * 256;  // pair pitch 256 (cols >=160 never read)
    for (int f = tid; f < SEQ * 160; f += NT) {
      int r = f / 160, c = f - r * 160;
      float v = (c < CIN) ? x[(size_t)b * (SEQ * CIN) + r * CIN + c] : 0.f;
      _Float16 h = (_Float16)v;
      int off = pidx(256, r, c);
      xH[off] = h;
      xL[off] = (_Float16)((v - (float)h) * LO_SCALE);
    }
    if (tid < DM) {  // row 0 = cls (t=0 -> identity swizzle)
      float v = cls_token[tid];
      _Float16 h = (_Float16)v;
      hH[tid] = h;
      hL[tid] = (_Float16)((v - (float)h) * LO_SCALE);
    }
    __syncthreads();
    for (int half = 0; half < 2; ++half) {
      f32x4 a1[1][4], a2[1][4];
#pragma unroll
      for (int tt = 0; tt < 4; ++tt) { a1[0][tt] = Z4; a2[0][tt] = Z4; }
      mfma_gemm2<4, 1, false, 0>(a1, a2, W_in, nullptr, nullptr, CIN,
                                 half * 128, 32, 8, xH, xL, 256, 64, 160, CIN,
                                 wave, lane);
#pragma unroll
      for (int tt = 0; tt < 4; ++tt) {
        int t = 16 * tt + cl;  // 0..63
        int o = half * 128 + wave * 16 + q4 * 4;
        f32x4 v;
#pragma unroll
        for (int rg = 0; rg < 4; ++rg) {
          int d = o + rg;
          float div = expf(-(float)(d & ~1) * (9.210340371976184f / 256.0f));
          float ang = (float)t * div;
          float pe = (d & 1) ? cosf(ang) : sinf(ang);
          v[rg] = a1[0][tt][rg] + a2[0][tt][rg] * LO_INV + b_in[d] + pe;
        }
        pair_store4(hH, hL, 256, t + 1, o, v);
      }
    }
  }
  __syncthreads();  // h ready before first qkv gemm

  // ---------------- transformer layers ----------------
  for (int li = 0; li < NL; ++li) {
    const float* Wqkv_l = Wqkv + (size_t)li * 768 * DM;
    const float* bqkv_l = bqkv + li * 768;
    const float* Wo_l = Wo + (size_t)li * DM * DM;
    const float* bo_l = bo + li * DM;
    const float* W1_l = W1 + (size_t)li * FFD * DM;
    const float* b1_l = b1 + li * FFD;
    const float* W2_l = W2 + (size_t)li * DM * FFD;
    const float* b2_l = b2 + li * DM;
    const _Float16* WqkvH_l = WH + (size_t)li * 768 * DM;
    const _Float16* WqkvL_l = WL + (size_t)li * 768 * DM;
    const _Float16* WoH_l = WH + OFF_WO + (size_t)li * DM * DM;
    const _Float16* WoL_l = WL + OFF_WO + (size_t)li * DM * DM;
    const _Float16* W1H_l = WH + OFF_W1 + (size_t)li * FFD * DM;
    const _Float16* W1L_l = WL + OFF_W1 + (size_t)li * FFD * DM;
    const _Float16* W2H_l = WH + OFF_W2 + (size_t)li * DM * FFD;
    const _Float16* W2L_l = WL + OFF_W2 + (size_t)li * DM * FFD;
    _Float16* oH = (_Float16*)obuf;          // attn-out pair [65][256]
    _Float16* oL = oH + 65 * 256;
    float* ex = obuf + 16640;                // 193 f32: q64, k64, scol, srow

    // ---- attention per head: qkv -> Q/K/VT (f32, scr) -> MFMA scores ->
    //      softmax on S[65][66] (overlays Qf/Kf) -> MFMA P@V -> o-pair ----
    for (int hd = 0; hd < NH; ++hd) {
      float* Qf = scr;            // [64][36]
      float* Kf = scr + 2304;     // [64][36]
      float* VT = scr + 4608;     // [32][66] (col 64 = t=64 row of v)
      float* Sb = scr;            // [65][66] overlays Qf/Kf
      {
        f32x4 a1[1][5], a2[1][5];
#pragma unroll
        for (int tt = 0; tt < 5; ++tt) { a1[0][tt] = Z4; a2[0][tt] = Z4; }
        // 6 o-tiles = 96 rows of Wqkv: q|k|v slices of head hd via rsel=256.
        if (usePre)
          mfma_gemm2<5, 1, true, 2>(a1, a2, nullptr, WqkvH_l, WqkvL_l, DM,
                                    hd * 32, 256, 6, hH, hL, 256, TT, DM, DM,
                                    wave, lane);
        else
          mfma_gemm2<5, 1, true, 1>(a1, a2, Wqkv_l, nullptr, nullptr, DM,
                                    hd * 32, 256, 6, hH, hL, 256, TT, DM, DM,
                                    wave, lane);
        __syncthreads();  // (1) prev head's Sb/VT reads done; scr writable
        if (wave < 6) {
#pragma unroll
          for (int tt = 0; tt < 5; ++tt) {
            int t = 16 * tt + cl;
            if (t < TT) {
#pragma unroll
              for (int rg = 0; rg < 4; ++rg) {
                int c = wave * 16 + q4 * 4 + rg;  // 0..95
                int d = c & 31;
                float v = a1[0][tt][rg] + a2[0][tt][rg] * LO_INV +
                          bqkv_l[(c >> 5) * 256 + hd * 32 + d];
                if (c < 32)      { if (t < 64) Qf[t * 36 + d] = v; else ex[d] = v; }
                else if (c < 64) { if (t < 64) Kf[t * 36 + d] = v; else ex[32 + d] = v; }
                else             VT[d * 66 + t] = v;
              }
            }
          }
        }
      }
      __syncthreads();  // (2) Q/K/VT ready
      // scores: waves 0-3 MFMA the 16 main tiles; waves 4-7 MFMA the fringe
      // (scol = Q.k64, srow = q64.K) via matvec tiles (vector in B row 0).
      f32x4 s1[4], s2[4];
      if (wave < 4) {
#pragma unroll
        for (int i = 0; i < 4; ++i) { s1[i] = Z4; s2[i] = Z4; }
        f16x8 bh, bl;
        split8_f4(&Kf[(16 * wave + cl) * 36 + 8 * q4], bh, bl);
#pragma unroll
        for (int rt = 0; rt < 4; ++rt) {
          f16x8 ah, al;
          split8_f4(&Qf[(16 * rt + cl) * 36 + 8 * q4], ah, al);
          s1[rt] = __builtin_amdgcn_mfma_f32_16x16x32_f16(ah, bh, s1[rt], 0, 0, 0);
          s2[rt] = __builtin_amdgcn_mfma_f32_16x16x32_f16(ah, bl, s2[rt], 0, 0, 0);
          s2[rt] = __builtin_amdgcn_mfma_f32_16x16x32_f16(al, bh, s2[rt], 0, 0, 0);
        }
      } else {
        const int tt4 = wave - 4;  // fringe tile (rows/cols 16*tt4..+15)
        // scol[t] = Q[t].k64: B row 0 = k64 (lanes cl==0), D col 0
        {
          float vv[8];
#pragma unroll
          for (int j = 0; j < 8; ++j) {
            float v = ex[32 + 8 * q4 + j];
            vv[j] = (cl == 0) ? v : 0.f;
          }
          f16x8 kh, kl;
          split8_arr(vv, kh, kl);
          f16x8 qh, ql;
          split8_f4(&Qf[(16 * tt4 + cl) * 36 + 8 * q4], qh, ql);
          f32x4 c1 = Z4, c2 = Z4;
          c1 = __builtin_amdgcn_mfma_f32_16x16x32_f16(qh, kh, c1, 0, 0, 0);
          c2 = __builtin_amdgcn_mfma_f32_16x16x32_f16(qh, kl, c2, 0, 0, 0);
          c2 = __builtin_amdgcn_mfma_f32_16x16x32_f16(ql, kh, c2, 0, 0, 0);
          if (cl == 0) {  // col 0 lanes; rows q4*4+rg
#pragma unroll
            for (int rg = 0; rg < 4; ++rg)
              ex[64 + 16 * tt4 + q4 * 4 + rg] = c1[rg] + c2[rg] * LO_INV;
          }
        }
        // srow[u] = q64.K[u]: A row 0 = q64, D row 0 (q4==0, reg 0)
        {
          float vv[8];
#pragma unroll
          for (int j = 0; j < 8; ++j) {
            float v = ex[8 * q4 + j];
            vv[j] = (cl == 0) ? v : 0.f;
          }
          f16x8 qh, ql;
          split8_arr(vv, qh, ql);
          f16x8 kh, kl;
          split8_f4(&Kf[(16 * tt4 + cl) * 36 + 8 * q4], kh, kl);
          f32x4 r1 = Z4, r2 = Z4;
          r1 = __builtin_amdgcn_mfma_f32_16x16x32_f16(qh, kh, r1, 0, 0, 0);
          r2 = __builtin_amdgcn_mfma_f32_16x16x32_f16(qh, kl, r2, 0, 0, 0);
          r2 = __builtin_amdgcn_mfma_f32_16x16x32_f16(ql, kh, r2, 0, 0, 0);
          if (q4 == 0) ex[128 + 16 * tt4 + cl] = r1[0] + r2[0] * LO_INV;
        }
        if (wave == 4) {  // s64 = q64.k64
          float p = ex[lane & 31] * ex[32 + (lane & 31)];
          p = wave_bsum(p) * 0.5f;  // both halves duplicate
          if (lane == 0) ex[128 + 64] = p;
        }
      }
      __syncthreads();  // (3) Q/K reads done; fringe written; S may overwrite
      if (wave < 4) {
#pragma unroll
        for (int rt = 0; rt < 4; ++rt)
#pragma unroll
          for (int rg = 0; rg < 4; ++rg)
            Sb[(rt * 16 + q4 * 4 + rg) * 66 + wave * 16 + cl] =
                s1[rt][rg] + s2[rt][rg] * LO_INV;
      } else if (wave == 4) {
        Sb[lane * 66 + 64] = ex[64 + lane];
      } else if (wave == 5) {
        Sb[64 * 66 + lane] = ex[128 + lane];
        if (lane == 0) Sb[64 * 66 + 64] = ex[128 + 64];
      }
      __syncthreads();  // (4) S complete
      {
        const float sc = 0.17677669529663687f;  // 1/sqrt(32)
        for (int t = wave; t < 65; t += 8) {
          float s = Sb[t * 66 + lane] * sc;
          float s64 = Sb[t * 66 + 64] * sc;
          float m = fmaxf(wave_bmax(s), s64);
          float e = __expf(s - m), e64 = __expf(s64 - m);
          float inv = 1.0f / (wave_bsum(e) + e64);
          Sb[t * 66 + lane] = e * inv;
          if (lane == 0) Sb[t * 66 + 64] = e64 * inv;
        }
      }
      __syncthreads();  // (5) P ready
      // P@V: 8 tiles (wave -> t-tile w>>1, d-tile w&1), swapped: D[d][t]
      {
        int rt = wave >> 1, ct = wave & 1;
        f32x4 o1 = Z4, o2 = Z4;
#pragma unroll
        for (int kc = 0; kc < 64; kc += 32) {
          f16x8 ph, pl, vh, vl;
          split8_f2(&Sb[(16 * rt + cl) * 66 + kc + 8 * q4], ph, pl);
          split8_f2(&VT[(16 * ct + cl) * 66 + kc + 8 * q4], vh, vl);
          o1 = __builtin_amdgcn_mfma_f32_16x16x32_f16(vh, ph, o1, 0, 0, 0);
          o2 = __builtin_amdgcn_mfma_f32_16x16x32_f16(vh, pl, o2, 0, 0, 0);
          o2 = __builtin_amdgcn_mfma_f32_16x16x32_f16(vl, ph, o2, 0, 0, 0);
        }
        int t = rt * 16 + cl;       // 0..63
        float p64 = Sb[t * 66 + 64];
        int ob = ct * 16 + q4 * 4;
        f32x4 v;
#pragma unroll
        for (int rg = 0; rg < 4; ++rg) {
          int d = ob + rg;
          v[rg] = o1[rg] + o2[rg] * LO_INV + p64 * VT[d * 66 + 64];  // u=64 fixup
        }
        pair_store4(oH, oL, 256, t, hd * 32 + ob, v);
      }
      if (wave == 0) {  // O row t=64 (scalar; overlaps next head's qkv gemm)
        int d = lane & 31, hf = lane >> 5;
        float o = 0.f;
        for (int u = hf * 32; u < hf * 32 + 32; ++u)
          o += Sb[64 * 66 + u] * VT[d * 66 + u];
        if (hf == 1) o += Sb[64 * 66 + 64] * VT[d * 66 + 64];
        o += __shfl_down(o, 32, 64);
        if (lane < 32) {
          int c = hd * 32 + d;
          _Float16 h = (_Float16)o;
          int off = pidx(256, 64, c);  // 64&7=0 -> identity
          oH[off] = h;
          oL[off] = (_Float16)((o - (float)h) * LO_SCALE);
        }
      }
    }
    __syncthreads();  // o-pair complete

    // ---- proj + residual: h += o @ Wo^T + bo (two CIT=1 half-calls); LN1 ----
    for (int half = 0; half < 2; ++half) {
      f32x4 a1[1][5], a2[1][5];
#pragma unroll
      for (int tt = 0; tt < 5; ++tt) { a1[0][tt] = Z4; a2[0][tt] = Z4; }
      if (usePre)
        mfma_gemm2<5, 1, false, 2>(a1, a2, nullptr, WoH_l, WoL_l, DM,
                                   half * 128, 32, 8, oH, oL, 256, TT, DM, DM,
                                   wave, lane);
      else
        mfma_gemm2<5, 1, false, 1>(a1, a2, Wo_l, nullptr, nullptr, DM,
                                   half * 128, 32, 8, oH, oL, 256, TT, DM, DM,
                                   wave, lane);
#pragma unroll
      for (int tt = 0; tt < 5; ++tt) {
        int t = 16 * tt + cl;
        if (t < TT) {
          int o = half * 128 + wave * 16 + q4 * 4;
          f32x4 r = pair_load4(hH, hL, 256, t, o);
          float4 b4 = *(const float4*)&bo_l[o];
          float bb[4] = {b4.x, b4.y, b4.z, b4.w};
          f32x4 v;
#pragma unroll
          for (int rg = 0; rg < 4; ++rg)
            v[rg] = r[rg] + a1[0][tt][rg] + a2[0][tt][rg] * LO_INV + bb[rg];
          pair_store4(hH, hL, 256, t, o, v);
        }
      }
    }
    __syncthreads();
    ln_rows_pair(hH, hL, ln1_g + li * DM, ln1_b + li * DM, wave, lane);
    __syncthreads();

    // ---- FF: T-split two-pass ----
    {
      _Float16* f1H = (_Float16*)obuf;
      _Float16* f1L = f1H + 33 * 512;
      if (usePre) {
        ff_block<2, 2>(0, 32, W1_l, b1_l, W2_l, b2_l, W1H_l, W1L_l, W2H_l,
                       W2L_l, hH, hL, f1H, f1L, wave, lane);
        __syncthreads();
        ff_block<3, 2>(32, 33, W1_l, b1_l, W2_l, b2_l, W1H_l, W1L_l, W2H_l,
                       W2L_l, hH, hL, f1H, f1L, wave, lane);
      } else {
        ff_block<2, 1>(0, 32, W1_l, b1_l, W2_l, b2_l, nullptr, nullptr,
                       nullptr, nullptr, hH, hL, f1H, f1L, wave, lane);
        __syncthreads();
        ff_block<3, 1>(32, 33, W1_l, b1_l, W2_l, b2_l, nullptr, nullptr,
                       nullptr, nullptr, hH, hL, f1H, f1L, wave, lane);
      }
    }
    __syncthreads();
    ln_rows_pair(hH, hL, ln2_g + li * DM, ln2_b + li * DM, wave, lane);
    __syncthreads();
  }

  // ---------------- head: lnf(cls) -> z_e -> VQ argmin -> decoder (exact fp32) ----------------
  if (tid < 64) {  // lnf on row 0 (t=0 -> identity swizzle) -> obuf[0..255]
    int c0 = 2 * lane, c1 = 128 + 2 * lane;
    float v0 = (float)hH[c0] + (float)hL[c0] * LO_INV;
    float v1 = (float)hH[c0 + 1] + (float)hL[c0 + 1] * LO_INV;
    float v2 = (float)hH[c1] + (float)hL[c1] * LO_INV;
    float v3 = (float)hH[c1 + 1] + (float)hL[c1 + 1] * LO_INV;
    float m = wave_bsum(v0 + v1 + v2 + v3) * (1.0f / 256.0f);
    float d0 = v0 - m, d1 = v1 - m, d2 = v2 - m, d3 = v3 - m;
    float var = wave_bsum(d0 * d0 + d1 * d1 + d2 * d2 + d3 * d3) * (1.0f / 256.0f);
    float rstd = 1.0f / sqrtf(var + 1e-5f);
    obuf[c0]     = d0 * rstd * lnf_g[c0]     + lnf_b[c0];
    obuf[c0 + 1] = d1 * rstd * lnf_g[c0 + 1] + lnf_b[c0 + 1];
    obuf[c1]     = d2 * rstd * lnf_g[c1]     + lnf_b[c1];
    obuf[c1 + 1] = d3 * rstd * lnf_g[c1 + 1] + lnf_b[c1 + 1];
  }
  __syncthreads();
  // z_e = lnf(cls) @ W_out^T + b_out -> obuf[256..384)
  for (int o = wave; o < ED; o += 8) {
    const float4 w4 = *(const float4*)&W_out[o * DM + lane * 4];
    const float4 c4 = *(const float4*)&obuf[lane * 4];
    float s = w4.x * c4.x + w4.y * c4.y + w4.z * c4.z + w4.w * c4.w;
    s = wave_bsum(s);
    if (lane == 0) obuf[256 + o] = s + b_out[o];
  }
  __syncthreads();

  // VQ argmin over |cb|^2 - 2 ze.cb (|ze|^2 constant); first-index tie-break
  float bestv = 3.4e38f;
  int bestk = 0;
  for (int ch = 0; ch < 8; ++ch) {
    __syncthreads();
    for (int f = tid; f < 128 * 128; f += NT) {  // stage cb chunk, rows padded to 129
      int r = f >> 7, c = f & 127;
      hbuf[r * 129 + c] = codebook[(size_t)(ch * 128 + r) * ED + c];
    }
    __syncthreads();
    {
      int kl = tid & 127, q = tid >> 7;
      float part = 0.f;
#pragma unroll 8
      for (int jj = 0; jj < 32; ++jj) {
        int e = q * 32 + jj;
        float cv = hbuf[kl * 129 + e];
        part += cv * (cv - 2.0f * obuf[256 + e]);
      }
      scr[kl * 4 + q] = part;
    }
    __syncthreads();
    if (tid < 128) {
      float d2v = scr[tid * 4] + scr[tid * 4 + 1] + scr[tid * 4 + 2] + scr[tid * 4 + 3];
      int kk = ch * 128 + tid;
      if (d2v < bestv) { bestv = d2v; bestk = kk; }  // ascending k per thread
    }
  }
  if (tid < 128) {
    scr[512 + tid] = bestv;
    scr[640 + tid] = __int_as_float(bestk);
  }
  __syncthreads();
  if (tid == 0) {
    float bv = 3.4e38f;
    int bk = 1 << 30;
    for (int j = 0; j < 128; ++j) {
      float v = scr[512 + j];
      int kk = __float_as_int(scr[640 + j]);
      if (v < bv || (v == bv && kk < bk)) { bv = v; bk = kk; }
    }
    scr[700] = __int_as_float(bk);
    out[2 * NB + b] = (float)bk;  // indices output (as float value)
  }
  __syncthreads();
  const int bk = __float_as_int(scr[700]);

  // z_q -> obuf[384..512); commitment + histogram
  if (tid < ED) {
    float zqv = codebook[(size_t)bk * ED + tid];
    obuf[384 + tid] = zqv;
    float df = zqv - obuf[256 + tid];
    float sq = wave_bsum(df * df);
    if ((tid & 63) == 0) atomicAdd(&ws[0], sq);
  }
  if (tid == 0) atomicAdd(&ws[1 + bk], 1.0f);
  __syncthreads();

  // decoder: d1 = zq @ Wd1^T + bd1 (256) -> LN -> gelu -> @Wd2^T (128) -> gelu -> @Wd3^T (2)
  for (int o = wave; o < DM; o += 8) {
    const float2 w2 = *(const float2*)&Wd1[o * ED + lane * 2];
    const float2 z2 = *(const float2*)&obuf[384 + lane * 2];
    float s = wave_bsum(w2.x * z2.x + w2.y * z2.y);
    if (lane == 0) obuf[512 + o] = s + bd1[o];
  }
  __syncthreads();
  if (tid < 64) {
    float v0 = obuf[512 + lane], v1 = obuf[512 + lane + 64];
    float v2 = obuf[512 + lane + 128], v3 = obuf[512 + lane + 192];
    float m = wave_bsum(v0 + v1 + v2 + v3) * (1.0f / 256.0f);
    float d0 = v0 - m, d1 = v1 - m, d2 = v2 - m, d3 = v3 - m;
    float var = wave_bsum(d0 * d0 + d1 * d1 + d2 * d2 + d3 * d3) * (1.0f / 256.0f);
    float rstd = 1.0f / sqrtf(var + 1e-5f);
    obuf[512 + lane]       = gelu_f(d0 * rstd * lnd_g[lane]       + lnd_b[lane]);
    obuf[512 + lane + 64]  = gelu_f(d1 * rstd * lnd_g[lane + 64]  + lnd_b[lane + 64]);
    obuf[512 + lane + 128] = gelu_f(d2 * rstd * lnd_g[lane + 128] + lnd_b[lane + 128]);
    obuf[512 + lane + 192] = gelu_f(d3 * rstd * lnd_g[lane + 192] + lnd_b[lane + 192]);
  }
  __syncthreads();
  for (int o = wave; o < ED; o += 8) {
    const float4 w4 = *(const float4*)&Wd2[o * DM + lane * 4];
    const float4 g4 = *(const float4*)&obuf[512 + lane * 4];
    float s = wave_bsum(w4.x * g4.x + w4.y * g4.y + w4.z * g4.z + w4.w * g4.w);
    if (lane == 0) obuf[768 + o] = gelu_f(s + bd2[o]);
  }
  __syncthreads();
  if (wave < 2) {
    const float2 w2 = *(const float2*)&Wd3[wave * ED + lane * 2];
    const float2 g2 = *(const float2*)&obuf[768 + lane * 2];
    float s = wave_bsum(w2.x * g2.x + w2.y * g2.y);
    if (lane == 0) out[b * 2 + wave] = s + bd3[wave];
  }
}

__global__ void vqvae_finish(const float* __restrict__ ws, float* __restrict__ out) {
  __shared__ float red[256];
  int tid = threadIdx.x;
  float part = 0.f;
  for (int k = tid; k < KCB; k += 256) {
    float p = ws[1 + k] * (1.0f / 2048.0f);
    part += p * logf(p + 1e-10f);
  }
  red[tid] = part;
  __syncthreads();
  for (int s = 128; s > 0; s >>= 1) {
    if (tid < s) red[tid] += red[tid + s];
    __syncthreads();
  }
  if (tid == 0) {
    out[2 * NB + NB]     = 0.1f * ws[0] * (1.0f / (2048.0f * 128.0f));  // commitment loss
    out[2 * NB + NB + 1] = expf(-red[0]);                               // perplexity
  }
}

extern "C" void kernel_launch(void* const* d_in, const int* in_sizes, int n_in,
                              void* d_out, int out_size, void* d_ws, size_t ws_size,
                              hipStream_t stream) {
  (void)in_sizes; (void)n_in; (void)out_size;
  const float* x         = (const float*)d_in[0];
  const float* W_in      = (const float*)d_in[1];
  const float* b_in      = (const float*)d_in[2];
  const float* cls_token = (const float*)d_in[3];
  const float* Wqkv      = (const float*)d_in[4];
  const float* bqkv      = (const float*)d_in[5];
  const float* Wo        = (const float*)d_in[6];
  const float* bo        = (const float*)d_in[7];
  const float* W1        = (const float*)d_in[8];
  const float* b1        = (const float*)d_in[9];
  const float* W2        = (const float*)d_in[10];
  const float* b2        = (const float*)d_in[11];
  const float* ln1_g     = (const float*)d_in[12];
  const float* ln1_b     = (const float*)d_in[13];
  const float* ln2_g     = (const float*)d_in[14];
  const float* ln2_b     = (const float*)d_in[15];
  const float* lnf_g     = (const float*)d_in[16];
  const float* lnf_b     = (const float*)d_in[17];
  const float* W_out     = (const float*)d_in[18];
  const float* b_out     = (const float*)d_in[19];
  const float* codebook  = (const float*)d_in[20];
  const float* Wd1       = (const float*)d_in[21];
  const float* bd1       = (const float*)d_in[22];
  const float* lnd_g     = (const float*)d_in[23];
  const float* lnd_b     = (const float*)d_in[24];
  const float* Wd2       = (const float*)d_in[25];
  const float* bd2       = (const float*)d_in[26];
  const float* Wd3       = (const float*)d_in[27];
  const float* bd3       = (const float*)d_in[28];
  float* out = (float*)d_out;
  float* ws = (float*)d_ws;

  const int usePre = (ws_size >= (size_t)WS_NEED) ? 1 : 0;

  hipLaunchKernelGGL(vqvae_zero, dim3(5), dim3(256), 0, stream, ws);
  if (usePre)
    hipLaunchKernelGGL(vqvae_prep, dim3(2048), dim3(512), 0, stream,
                       Wqkv, Wo, W1, W2, ws);
  hipLaunchKernelGGL(vqvae_main, dim3(NB), dim3(NT), 0, stream,
                     x, W_in, b_in, cls_token, Wqkv, bqkv, Wo, bo, W1, b1, W2, b2,
                     ln1_g, ln1_b, ln2_g, ln2_b, lnf_g, lnf_b, W_out, b_out,
                     codebook, Wd1, bd1, lnd_g, lnd_b, Wd2, bd2, Wd3, bd3, out,
                     ws, usePre);
  hipLaunchKernelGGL(vqvae_finish, dim3(1), dim3(256), 0, stream, ws, out);
}